// Round 3
// baseline (475.006 us; speedup 1.0000x reference)
//
#include <hip/hip_runtime.h>

typedef __bf16 bf16x8 __attribute__((ext_vector_type(8)));
typedef float f32x4 __attribute__((ext_vector_type(4)));

__device__ __forceinline__ unsigned short f2bf(float f) {
  unsigned int u = __builtin_bit_cast(unsigned int, f);
  u += 0x7fffu + ((u >> 16) & 1u);
  return (unsigned short)(u >> 16);
}

__device__ __forceinline__ void async16(const void* g, void* l) {
  __builtin_amdgcn_global_load_lds(
      (const __attribute__((address_space(1))) unsigned int*)g,
      (__attribute__((address_space(3))) unsigned int*)l, 16, 0, 0);
}

// ---------------------------------------------------------------------------
// pack: fp32 -> bf16 (RNE), vectorized
// ---------------------------------------------------------------------------
__global__ __launch_bounds__(256) void pack_bf16(const float* __restrict__ src,
                                                 unsigned short* __restrict__ dst,
                                                 long n) {
  long i = ((long)blockIdx.x * blockDim.x + threadIdx.x) * 4;
  long stride = (long)gridDim.x * blockDim.x * 4;
  for (; i < n; i += stride) {
    float4 v = *(const float4*)(src + i);
    ushort4 o;
    o.x = f2bf(v.x); o.y = f2bf(v.y); o.z = f2bf(v.z); o.w = f2bf(v.w);
    *(ushort4*)(dst + i) = o;
  }
}

// ---------------------------------------------------------------------------
// gemm_bt: C[M,N] = A[M,K] * B[N,K]^T   (both row-major bf16, K contiguous)
// 128x128 tile, BK=64, 4 waves (2x2 of 64x64), 16x16x32 bf16 MFMA.
// global_load_lds width 16, inverse-swizzled SOURCE + XOR-swizzled ds_read.
// EPI 0: bf16 out into QKV buffer + bias.  EPI 1: fp32 out * scale.
// ---------------------------------------------------------------------------
template <int EPI>
__global__ __launch_bounds__(256) void gemm_bt(
    const unsigned short* __restrict__ A, long sAz,
    const unsigned short* __restrict__ B, long sBz,
    int lda, int ldb, int ksteps,
    float* __restrict__ Cf, long sCz, int ldc, float scale,
    unsigned short* __restrict__ Cq,
    const float* __restrict__ bq, const float* __restrict__ bk,
    const float* __restrict__ bv) {
  __shared__ __align__(16) char smem[32768];
  char* ldsA = smem;
  char* ldsB = smem + 16384;

  const int tid = threadIdx.x;
  const int l = tid & 63;
  const int w = tid >> 6;
  const int wm = w >> 1, wn = w & 1;
  const int bm = blockIdx.x, bn = blockIdx.y, bz = blockIdx.z;

  const unsigned short* Ab = A + (long)bz * sAz + (long)bm * 128 * lda;
  const unsigned short* Bb = B + (long)bz * sBz + (long)bn * 128 * ldb;

  f32x4 acc[4][4] = {};

  const int l15 = l & 15;
  const int kof = (l >> 4) << 3;  // 0,8,16,24

  for (int kk = 0; kk < ksteps; ++kk) {
    const unsigned short* As = Ab + kk * 64;
    const unsigned short* Bs = Bb + kk * 64;
#pragma unroll
    for (int i = 0; i < 4; ++i) {  // A tile: 128 rows x 64 cols bf16 = 16KB
      int c = i * 256 + tid;
      int row = c >> 3, ch = c & 7;
      int sch = ch ^ (row & 7);  // inverse swizzle on SOURCE
      async16(As + (long)row * lda + sch * 8, ldsA + i * 4096 + w * 1024);
    }
#pragma unroll
    for (int i = 0; i < 4; ++i) {  // B tile
      int c = i * 256 + tid;
      int row = c >> 3, ch = c & 7;
      int sch = ch ^ (row & 7);
      async16(Bs + (long)row * ldb + sch * 8, ldsB + i * 4096 + w * 1024);
    }
    asm volatile("s_waitcnt vmcnt(0)" ::: "memory");
    __syncthreads();
#pragma unroll
    for (int ks = 0; ks < 2; ++ks) {
      bf16x8 af[4], bfr[4];
#pragma unroll
      for (int i = 0; i < 4; ++i) {
        int row = wm * 64 + i * 16 + l15;
        int byte = (row << 7) + ((ks * 32 + kof) << 1);
        byte ^= (row & 7) << 4;
        af[i] = *(const bf16x8*)(ldsA + byte);
      }
#pragma unroll
      for (int j = 0; j < 4; ++j) {
        int row = wn * 64 + j * 16 + l15;
        int byte = (row << 7) + ((ks * 32 + kof) << 1);
        byte ^= (row & 7) << 4;
        bfr[j] = *(const bf16x8*)(ldsB + byte);
      }
#pragma unroll
      for (int i = 0; i < 4; ++i)
#pragma unroll
        for (int j = 0; j < 4; ++j)
          acc[i][j] = __builtin_amdgcn_mfma_f32_16x16x32_bf16(af[i], bfr[j],
                                                              acc[i][j], 0, 0, 0);
    }
    __syncthreads();
  }

  // epilogue: C/D layout col=lane&15, row=(lane>>4)*4+reg (m89-verified)
  const int rbase = bm * 128 + wm * 64;
  const int cbase = bn * 128 + wn * 64;
  const int rl = (l >> 4) * 4;

  if constexpr (EPI == 0) {
    const int which = cbase >> 10;  // 0=Q 1=K 2=V (N tiles never straddle)
    const int cw = cbase & 1023;
    unsigned short* dst = Cq + (long)which * (8L * 2048 * 1024);
    const float* bias = (which == 0) ? bq : (which == 1) ? bk : bv;
#pragma unroll
    for (int j = 0; j < 4; ++j) {
      int cc = cw + j * 16 + l15;
      float bias_v = bias[cc];
#pragma unroll
      for (int i = 0; i < 4; ++i)
#pragma unroll
        for (int r = 0; r < 4; ++r) {
          int rr = rbase + i * 16 + rl + r;
          dst[(long)rr * 1024 + cc] = f2bf(acc[i][j][r] + bias_v);
        }
    }
  } else {
    float* C = Cf + (long)bz * sCz;
#pragma unroll
    for (int i = 0; i < 4; ++i)
#pragma unroll
      for (int r = 0; r < 4; ++r) {
        long rr = rbase + i * 16 + rl + r;
#pragma unroll
        for (int j = 0; j < 4; ++j)
          C[rr * ldc + cbase + j * 16 + l15] = acc[i][j][r] * scale;
      }
  }
}

// ---------------------------------------------------------------------------
// transpose V: [B,2048,1024] bf16 -> [B,1024,2048] bf16, 64x64 LDS tiles
// ---------------------------------------------------------------------------
__global__ __launch_bounds__(256) void transpose64(
    const unsigned short* __restrict__ V, unsigned short* __restrict__ Vt) {
  __shared__ unsigned short t[64][68];
  int b = blockIdx.z;
  int s0 = blockIdx.x * 64, d0 = blockIdx.y * 64;
  const unsigned short* src = V + (long)b * 2048 * 1024;
  unsigned short* dst = Vt + (long)b * 1024 * 2048;
  int r = threadIdx.x >> 4, c = threadIdx.x & 15;
#pragma unroll
  for (int i = 0; i < 4; ++i) {
    int row = i * 16 + r;
    const ushort2* p = (const ushort2*)(src + (long)(s0 + row) * 1024 + d0 + c * 4);
    ushort2 v0 = p[0], v1 = p[1];
    t[row][c * 4 + 0] = v0.x; t[row][c * 4 + 1] = v0.y;
    t[row][c * 4 + 2] = v1.x; t[row][c * 4 + 3] = v1.y;
  }
  __syncthreads();
#pragma unroll
  for (int i = 0; i < 4; ++i) {
    int drow = i * 16 + r;
    ushort2 o0, o1;
    o0.x = t[c * 4 + 0][drow]; o0.y = t[c * 4 + 1][drow];
    o1.x = t[c * 4 + 2][drow]; o1.y = t[c * 4 + 3][drow];
    ushort2* q = (ushort2*)(dst + (long)(d0 + drow) * 2048 + s0 + c * 4);
    q[0] = o0; q[1] = o1;
  }
}

// ---------------------------------------------------------------------------
// row softmax: fp32 scores [nrows x 2048] -> bf16 weights [nrows x 2048]
// DISJOINT output buffer (no in-place aliasing). One block per row.
// ---------------------------------------------------------------------------
__global__ __launch_bounds__(256) void softmax_rows(
    const float* __restrict__ S, unsigned short* __restrict__ W) {
  long row = blockIdx.x;
  const float* p = S + row * 2048;
  int t = threadIdx.x;
  float4 v0 = *(const float4*)(p + t * 4);
  float4 v1 = *(const float4*)(p + 1024 + t * 4);
  float m = fmaxf(fmaxf(fmaxf(v0.x, v0.y), fmaxf(v0.z, v0.w)),
                  fmaxf(fmaxf(v1.x, v1.y), fmaxf(v1.z, v1.w)));
#pragma unroll
  for (int o = 32; o; o >>= 1) m = fmaxf(m, __shfl_xor(m, o));
  __shared__ float redm[4];
  __shared__ float reds[4];
  int wv = t >> 6;
  if ((t & 63) == 0) redm[wv] = m;
  __syncthreads();
  m = fmaxf(fmaxf(redm[0], redm[1]), fmaxf(redm[2], redm[3]));
  float e[8];
  e[0] = __expf(v0.x - m); e[1] = __expf(v0.y - m);
  e[2] = __expf(v0.z - m); e[3] = __expf(v0.w - m);
  e[4] = __expf(v1.x - m); e[5] = __expf(v1.y - m);
  e[6] = __expf(v1.z - m); e[7] = __expf(v1.w - m);
  float s = e[0] + e[1] + e[2] + e[3] + e[4] + e[5] + e[6] + e[7];
#pragma unroll
  for (int o = 32; o; o >>= 1) s += __shfl_xor(s, o);
  if ((t & 63) == 0) reds[wv] = s;
  __syncthreads();
  s = reds[0] + reds[1] + reds[2] + reds[3];
  float inv = 1.0f / s;
  ushort4 a, b;
  a.x = f2bf(e[0] * inv); a.y = f2bf(e[1] * inv);
  a.z = f2bf(e[2] * inv); a.w = f2bf(e[3] * inv);
  b.x = f2bf(e[4] * inv); b.y = f2bf(e[5] * inv);
  b.z = f2bf(e[6] * inv); b.w = f2bf(e[7] * inv);
  *(ushort4*)(W + row * 2048 + t * 4) = a;
  *(ushort4*)(W + row * 2048 + 1024 + t * 4) = b;
}

__global__ void sentinel_kernel(float* out, float v) { out[0] = v; }

// ---------------------------------------------------------------------------
extern "C" void kernel_launch(void* const* d_in, const int* in_sizes, int n_in,
                              void* d_out, int out_size, void* d_ws, size_t ws_size,
                              hipStream_t stream) {
  const float* x  = (const float*)d_in[0];
  const float* Wq = (const float*)d_in[1];
  const float* bq = (const float*)d_in[2];
  const float* Wk = (const float*)d_in[3];
  const float* bk = (const float*)d_in[4];
  const float* Wv = (const float*)d_in[5];
  const float* bv = (const float*)d_in[6];
  float* out = (float*)d_out;

  // Two layouts, chosen by ws_size (constant across calls -> same work each call):
  //  FULL (>=224395264 B): fully disjoint, zero aliasing:
  //    qkv[0,96M) xb[96M,128M) wb[128M,134M) vt[134M,166M) sc[166M,198M) wt[198M,214M)
  //    4 passes x 2 batches.
  //  MIN  (>=140509184 B): qkv[0,96M) vt=xb[96M,128M) wb[128M,134M)
  //    sc[64M,80M) wt[80M,88M)  (both inside the DEAD V region; all aliasing is
  //    write-full-then-read across kernel boundaries; nothing in-place)
  //    8 passes x 1 batch.
  const size_t NEED_FULL = 224395264;
  const size_t NEED_MIN  = 140509184;
  if (ws_size < NEED_MIN) {
    sentinel_kernel<<<1, 1, 0, stream>>>(out, (float)ws_size);
    return;
  }
  const bool full = (ws_size >= NEED_FULL);
  char* ws = (char*)d_ws;
  unsigned short* qkv = (unsigned short*)(ws);
  unsigned short* xb  = (unsigned short*)(ws + 100663296);
  unsigned short* wb  = (unsigned short*)(ws + 134217728);
  unsigned short* vt  = full ? (unsigned short*)(ws + 140509184)
                             : (unsigned short*)(ws + 100663296);  // reuses dead xb
  float*          sc  = full ? (float*)(ws + 174063616)
                             : (float*)(ws + 67108864);            // dead V, 1st half
  unsigned short* wt  = full ? (unsigned short*)(ws + 207618048)
                             : (unsigned short*)(ws + 83886080);   // dead V, 2nd half

  const float scale = 0.03125f;  // 1/sqrt(1024)

  pack_bf16<<<dim3(4096), dim3(256), 0, stream>>>(x, xb, 16777216L);
  pack_bf16<<<dim3(1024), dim3(256), 0, stream>>>(Wq, wb, 1048576L);
  pack_bf16<<<dim3(1024), dim3(256), 0, stream>>>(Wk, wb + 1048576, 1048576L);
  pack_bf16<<<dim3(1024), dim3(256), 0, stream>>>(Wv, wb + 2097152, 1048576L);

  // QKV projection: [16384,1024] x [3072,1024]^T -> qkv bf16 (+bias)
  gemm_bt<0><<<dim3(128, 24, 1), dim3(256), 0, stream>>>(
      xb, 0L, wb, 0L, 1024, 1024, 16,
      nullptr, 0L, 0, 1.0f, qkv, bq, bk, bv);

  // V^T per batch
  transpose64<<<dim3(32, 16, 8), dim3(256), 0, stream>>>(qkv + 2L * 16777216, vt);

  const int batches_per_pass = full ? 2 : 1;
  const int npasses = 8 / batches_per_pass;
  for (int p = 0; p < npasses; ++p) {
    long b0 = (long)p * batches_per_pass;
    long boff = b0 * 2048 * 1024;  // elem offset into per-batch [2048,1024]
    // scores = Q K^T * scale : [2048,1024] x [2048,1024]^T -> fp32 sc
    gemm_bt<1><<<dim3(16, 16, batches_per_pass), dim3(256), 0, stream>>>(
        qkv + boff, 2048L * 1024, qkv + 16777216 + boff, 2048L * 1024,
        1024, 1024, 16,
        sc, 2048L * 2048, 2048, scale, nullptr, nullptr, nullptr, nullptr);

    // softmax rows -> bf16 weights (disjoint buffer)
    softmax_rows<<<dim3(2048 * batches_per_pass), dim3(256), 0, stream>>>(sc, wt);

    // out = weights @ V^T-rows : [2048,2048] x [1024,2048]^T -> fp32
    gemm_bt<1><<<dim3(16, 8, batches_per_pass), dim3(256), 0, stream>>>(
        wt, 2048L * 2048, vt + b0 * 1024 * 2048, 1024L * 2048,
        2048, 2048, 32,
        out + boff, 2048L * 1024, 1024, 1.0f, nullptr, nullptr, nullptr, nullptr);
  }
}

// Round 4
// 376.228 us; speedup vs baseline: 1.2625x; 1.2625x over previous
//
#include <hip/hip_runtime.h>

typedef __bf16 bf16x8 __attribute__((ext_vector_type(8)));
typedef float f32x4 __attribute__((ext_vector_type(4)));
typedef _Float16 f16x8v __attribute__((ext_vector_type(8)));
typedef unsigned short u16x8 __attribute__((ext_vector_type(8)));

__device__ __forceinline__ unsigned short f2bf(float f) {
  unsigned int u = __builtin_bit_cast(unsigned int, f);
  u += 0x7fffu + ((u >> 16) & 1u);
  return (unsigned short)(u >> 16);
}

__device__ __forceinline__ unsigned short f2h(float f) {
  _Float16 h = (_Float16)f;
  return __builtin_bit_cast(unsigned short, h);
}

__device__ __forceinline__ void async16(const void* g, void* l) {
  __builtin_amdgcn_global_load_lds(
      (const __attribute__((address_space(1))) unsigned int*)g,
      (__attribute__((address_space(3))) unsigned int*)l, 16, 0, 0);
}

// ---------------------------------------------------------------------------
// pack: fp32 -> bf16 (RNE), vectorized
// ---------------------------------------------------------------------------
__global__ __launch_bounds__(256) void pack_bf16(const float* __restrict__ src,
                                                 unsigned short* __restrict__ dst,
                                                 long n) {
  long i = ((long)blockIdx.x * blockDim.x + threadIdx.x) * 4;
  long stride = (long)gridDim.x * blockDim.x * 4;
  for (; i < n; i += stride) {
    float4 v = *(const float4*)(src + i);
    ushort4 o;
    o.x = f2bf(v.x); o.y = f2bf(v.y); o.z = f2bf(v.z); o.w = f2bf(v.w);
    *(ushort4*)(dst + i) = o;
  }
}

// ---------------------------------------------------------------------------
// gemm_bt: C[M,N] = A[M,K] * B[N,K]^T   (row-major bf16, K contiguous)
// 128x128 tile, BK=64, 4 waves (2x2 of 64x64), 16x16x32 bf16 MFMA.
// EPI 0: bf16 out + bias into QKV (which = col/1024), LDS-staged coalesced.
// EPI 1: fp32 out * scale, scalar stores (64B runs - acceptable).
// EPI 2: fp16 out * scale (scores), LDS-staged coalesced.
// XCD swizzle on bm when gridDim.x % 8 == 0.
// ---------------------------------------------------------------------------
template <int EPI>
__global__ __launch_bounds__(256) void gemm_bt(
    const unsigned short* __restrict__ A, long sAz,
    const unsigned short* __restrict__ B, long sBz,
    int lda, int ldb, int ksteps,
    float* __restrict__ Cf, long sCz, int ldc, float scale,
    unsigned short* __restrict__ Cq, long sQz, int ldq,
    const float* __restrict__ bq, const float* __restrict__ bk,
    const float* __restrict__ bv) {
  __shared__ __align__(16) char smem[32768];
  char* ldsA = smem;
  char* ldsB = smem + 16384;

  const int tid = threadIdx.x;
  const int l = tid & 63;
  const int w = tid >> 6;
  const int wm = w >> 1, wn = w & 1;
  int bm = blockIdx.x;
  if ((gridDim.x & 7) == 0) {  // XCD-aware swizzle (bijective: gx % 8 == 0)
    int cpx = gridDim.x >> 3;
    bm = (bm & 7) * cpx + (bm >> 3);
  }
  const int bn = blockIdx.y, bz = blockIdx.z;

  const unsigned short* Ab = A + (long)bz * sAz + (long)bm * 128 * lda;
  const unsigned short* Bb = B + (long)bz * sBz + (long)bn * 128 * ldb;

  f32x4 acc[4][4] = {};

  const int l15 = l & 15;
  const int kof = (l >> 4) << 3;  // 0,8,16,24

  for (int kk = 0; kk < ksteps; ++kk) {
    const unsigned short* As = Ab + kk * 64;
    const unsigned short* Bs = Bb + kk * 64;
#pragma unroll
    for (int i = 0; i < 4; ++i) {  // A tile: 128 rows x 64 cols bf16 = 16KB
      int c = i * 256 + tid;
      int row = c >> 3, ch = c & 7;
      int sch = ch ^ (row & 7);  // inverse swizzle on SOURCE
      async16(As + (long)row * lda + sch * 8, ldsA + i * 4096 + w * 1024);
    }
#pragma unroll
    for (int i = 0; i < 4; ++i) {  // B tile
      int c = i * 256 + tid;
      int row = c >> 3, ch = c & 7;
      int sch = ch ^ (row & 7);
      async16(Bs + (long)row * ldb + sch * 8, ldsB + i * 4096 + w * 1024);
    }
    asm volatile("s_waitcnt vmcnt(0)" ::: "memory");
    __syncthreads();
#pragma unroll
    for (int ks = 0; ks < 2; ++ks) {
      bf16x8 af[4], bfr[4];
#pragma unroll
      for (int i = 0; i < 4; ++i) {
        int row = wm * 64 + i * 16 + l15;
        int byte = (row << 7) + ((ks * 32 + kof) << 1);
        byte ^= (row & 7) << 4;
        af[i] = *(const bf16x8*)(ldsA + byte);
      }
#pragma unroll
      for (int j = 0; j < 4; ++j) {
        int row = wn * 64 + j * 16 + l15;
        int byte = (row << 7) + ((ks * 32 + kof) << 1);
        byte ^= (row & 7) << 4;
        bfr[j] = *(const bf16x8*)(ldsB + byte);
      }
#pragma unroll
      for (int i = 0; i < 4; ++i)
#pragma unroll
        for (int j = 0; j < 4; ++j)
          acc[i][j] = __builtin_amdgcn_mfma_f32_16x16x32_bf16(af[i], bfr[j],
                                                              acc[i][j], 0, 0, 0);
    }
    __syncthreads();
  }

  // C/D layout: col = lane&15 (+j*16), row = (lane>>4)*4 + r (+i*16)
  const int rl = (l >> 4) * 4;

  if constexpr (EPI == 1) {
    const int rbase = bm * 128 + wm * 64;
    const int cbase = bn * 128 + wn * 64;
    float* C = Cf + (long)bz * sCz;
#pragma unroll
    for (int i = 0; i < 4; ++i)
#pragma unroll
      for (int r = 0; r < 4; ++r) {
        long rr = rbase + i * 16 + rl + r;
#pragma unroll
        for (int j = 0; j < 4; ++j)
          C[rr * ldc + cbase + j * 16 + l15] = acc[i][j][r] * scale;
      }
  } else {
    // staged epilogue: wave tile 64x64 ushort in LDS (XOR-swizzled), then
    // 256B-contiguous dwordx4 stores (full 128x128 block tile row-major).
    const int colbase = bn * 128 + wn * 64;      // absolute col of this wave
    const float* bias = nullptr;
    if constexpr (EPI == 0)
      bias = ((colbase >> 10) == 0) ? bq : ((colbase >> 10) == 1) ? bk : bv;
#pragma unroll
    for (int i = 0; i < 4; ++i)
#pragma unroll
      for (int j = 0; j < 4; ++j) {
        int lc = j * 16 + l15;
        float bv_ = 0.0f;
        if constexpr (EPI == 0) bv_ = bias[(colbase + lc) & 1023];
#pragma unroll
        for (int r = 0; r < 4; ++r) {
          int lr = i * 16 + rl + r;
          int byte = w * 8192 + lr * 128 + lc * 2;
          byte ^= (lr & 7) << 4;
          unsigned short q;
          if constexpr (EPI == 0) q = f2bf(acc[i][j][r] + bv_);
          else                    q = f2h(acc[i][j][r] * scale);
          *(unsigned short*)(smem + byte) = q;
        }
      }
    __syncthreads();
    const long brow = (long)bm * 128;
    const int which = (bn * 128) >> 10;
    const int cw0 = (bn * 128) & 1023;
#pragma unroll
    for (int m = 0; m < 8; ++m) {
      int flat = m * 256 + tid;
      int row = flat >> 4, ch = flat & 15;
      int wv = ((row >> 6) << 1) | (ch >> 3);
      int byte = wv * 8192 + (row & 63) * 128 + (ch & 7) * 16;
      byte ^= (row & 7) << 4;
      uint4 val = *(const uint4*)(smem + byte);
      if constexpr (EPI == 0) {
        unsigned short* d = Cq + (long)which * (8L * 2048 * 1024) +
                            (brow + row) * 1024 + cw0 + ch * 8;
        *(uint4*)d = val;
      } else {
        unsigned short* d = Cq + (long)bz * sQz + (brow + row) * ldq +
                            bn * 128 + ch * 8;
        *(uint4*)d = val;
      }
    }
  }
}

// ---------------------------------------------------------------------------
// transpose V: [B,2048,1024] bf16 -> [B,1024,2048] bf16, 64x64 LDS tiles
// ---------------------------------------------------------------------------
__global__ __launch_bounds__(256) void transpose64(
    const unsigned short* __restrict__ V, unsigned short* __restrict__ Vt) {
  __shared__ unsigned short t[64][68];
  int b = blockIdx.z;
  int s0 = blockIdx.x * 64, d0 = blockIdx.y * 64;
  const unsigned short* src = V + (long)b * 2048 * 1024;
  unsigned short* dst = Vt + (long)b * 1024 * 2048;
  int r = threadIdx.x >> 4, c = threadIdx.x & 15;
#pragma unroll
  for (int i = 0; i < 4; ++i) {
    int row = i * 16 + r;
    const ushort2* p = (const ushort2*)(src + (long)(s0 + row) * 1024 + d0 + c * 4);
    ushort2 v0 = p[0], v1 = p[1];
    t[row][c * 4 + 0] = v0.x; t[row][c * 4 + 1] = v0.y;
    t[row][c * 4 + 2] = v1.x; t[row][c * 4 + 3] = v1.y;
  }
  __syncthreads();
#pragma unroll
  for (int i = 0; i < 4; ++i) {
    int drow = i * 16 + r;
    ushort2 o0, o1;
    o0.x = t[c * 4 + 0][drow]; o0.y = t[c * 4 + 1][drow];
    o1.x = t[c * 4 + 2][drow]; o1.y = t[c * 4 + 3][drow];
    ushort2* q = (ushort2*)(dst + (long)(d0 + drow) * 2048 + s0 + c * 4);
    q[0] = o0; q[1] = o1;
  }
}

// ---------------------------------------------------------------------------
// row softmax: fp16 scores [nrows x 2048] -> bf16 weights [nrows x 2048]
// one 256-thread block per row, 8 elems/thread, disjoint output buffer
// ---------------------------------------------------------------------------
__global__ __launch_bounds__(256) void softmax_rows_h(
    const unsigned short* __restrict__ S, unsigned short* __restrict__ W) {
  long row = blockIdx.x;
  int t = threadIdx.x;
  f16x8v hv = *(const f16x8v*)(S + row * 2048 + t * 8);
  float v[8];
#pragma unroll
  for (int k = 0; k < 8; ++k) v[k] = (float)hv[k];
  float m = v[0];
#pragma unroll
  for (int k = 1; k < 8; ++k) m = fmaxf(m, v[k]);
#pragma unroll
  for (int o = 32; o; o >>= 1) m = fmaxf(m, __shfl_xor(m, o));
  __shared__ float redm[4];
  __shared__ float reds[4];
  int wv = t >> 6;
  if ((t & 63) == 0) redm[wv] = m;
  __syncthreads();
  m = fmaxf(fmaxf(redm[0], redm[1]), fmaxf(redm[2], redm[3]));
  float e[8], s = 0.0f;
#pragma unroll
  for (int k = 0; k < 8; ++k) { e[k] = __expf(v[k] - m); s += e[k]; }
#pragma unroll
  for (int o = 32; o; o >>= 1) s += __shfl_xor(s, o);
  if ((t & 63) == 0) reds[wv] = s;
  __syncthreads();
  s = reds[0] + reds[1] + reds[2] + reds[3];
  float inv = 1.0f / s;
  u16x8 o;
#pragma unroll
  for (int k = 0; k < 8; ++k) o[k] = f2bf(e[k] * inv);
  *(u16x8*)(W + row * 2048 + t * 8) = o;
}

__global__ void sentinel_kernel(float* out, float v) { out[0] = v; }

// ---------------------------------------------------------------------------
extern "C" void kernel_launch(void* const* d_in, const int* in_sizes, int n_in,
                              void* d_out, int out_size, void* d_ws, size_t ws_size,
                              hipStream_t stream) {
  const float* x  = (const float*)d_in[0];
  const float* Wq = (const float*)d_in[1];
  const float* bq = (const float*)d_in[2];
  const float* Wk = (const float*)d_in[3];
  const float* bk = (const float*)d_in[4];
  const float* Wv = (const float*)d_in[5];
  const float* bv = (const float*)d_in[6];
  float* out = (float*)d_out;

  // Tiers (chosen by ws_size, constant across calls):
  //  BIG (>=207618048): z=8 single-dispatch attention phases.
  //    Q[0,33.5M) K[33.5,67.1) V[67.1,100.7) vt/xb'[100.7,134.2) wb[134.2,140.5)
  //    sc fp16 [140.5,207.6)  (xb aliases sc start; dead before sc written)
  //    wt bf16 [0,67.1)       (aliases Q+K, dead after scores gemm)
  //  MID (>=140509184): 4 passes x z=2; sc fp16 [67.1,83.9) wt [83.9,100.7)
  //    both inside dead-V region; vt aliases dead xb. (round-3-verified sizes)
  const size_t NEED_BIG = 207618048;
  const size_t NEED_MID = 140509184;
  if (ws_size < NEED_MID) {
    sentinel_kernel<<<1, 1, 0, stream>>>(out, (float)ws_size);
    return;
  }
  const bool big = (ws_size >= NEED_BIG);
  char* ws = (char*)d_ws;
  unsigned short* qkv = (unsigned short*)(ws);
  unsigned short* vt  = (unsigned short*)(ws + 100663296);
  unsigned short* wb  = (unsigned short*)(ws + 134217728);
  unsigned short* xb  = big ? (unsigned short*)(ws + 140509184)
                            : (unsigned short*)(ws + 100663296);
  unsigned short* sc  = big ? (unsigned short*)(ws + 140509184)
                            : (unsigned short*)(ws + 67108864);
  unsigned short* wt  = big ? (unsigned short*)(ws)
                            : (unsigned short*)(ws + 83886080);

  const float scale = 0.03125f;  // 1/sqrt(1024)

  pack_bf16<<<dim3(4096), dim3(256), 0, stream>>>(x, xb, 16777216L);
  pack_bf16<<<dim3(1024), dim3(256), 0, stream>>>(Wq, wb, 1048576L);
  pack_bf16<<<dim3(1024), dim3(256), 0, stream>>>(Wk, wb + 1048576, 1048576L);
  pack_bf16<<<dim3(1024), dim3(256), 0, stream>>>(Wv, wb + 2097152, 1048576L);

  // QKV projection: [16384,1024] x [3072,1024]^T -> qkv bf16 (+bias)
  gemm_bt<0><<<dim3(128, 24, 1), dim3(256), 0, stream>>>(
      xb, 0L, wb, 0L, 1024, 1024, 16,
      nullptr, 0L, 0, 1.0f, qkv, 0L, 1024, bq, bk, bv);

  // V^T per batch (vt overwrites dead-xb region)
  transpose64<<<dim3(32, 16, 8), dim3(256), 0, stream>>>(qkv + 2L * 16777216, vt);

  const int bpp = big ? 8 : 2;        // batches per pass
  const int npasses = 8 / bpp;
  for (int p = 0; p < npasses; ++p) {
    long b0 = (long)p * bpp;
    long boff = b0 * 2048 * 1024;
    // scores = Q K^T * scale -> fp16 sc
    gemm_bt<2><<<dim3(16, 16, bpp), dim3(256), 0, stream>>>(
        qkv + boff, 2048L * 1024, qkv + 16777216 + boff, 2048L * 1024,
        1024, 1024, 16,
        nullptr, 0L, 0, scale, sc, 2048L * 2048, 2048, nullptr, nullptr, nullptr);

    // softmax rows -> bf16 weights
    softmax_rows_h<<<dim3(2048 * bpp), dim3(256), 0, stream>>>(sc, wt);

    // out = weights @ V^T-rows -> fp32
    gemm_bt<1><<<dim3(16, 8, bpp), dim3(256), 0, stream>>>(
        wt, 2048L * 2048, vt + b0 * 1024 * 2048, 1024L * 2048,
        2048, 2048, 32,
        out + boff, 2048L * 1024, 1024, 1.0f, nullptr, 0L, 0,
        nullptr, nullptr, nullptr);
  }
}

// Round 5
// 327.218 us; speedup vs baseline: 1.4516x; 1.1498x over previous
//
#include <hip/hip_runtime.h>

typedef __bf16 bf16x8 __attribute__((ext_vector_type(8)));
typedef float f32x4 __attribute__((ext_vector_type(4)));
typedef _Float16 f16x8v __attribute__((ext_vector_type(8)));
typedef unsigned short u16x8 __attribute__((ext_vector_type(8)));

__device__ __forceinline__ unsigned short f2bf(float f) {
  unsigned int u = __builtin_bit_cast(unsigned int, f);
  u += 0x7fffu + ((u >> 16) & 1u);
  return (unsigned short)(u >> 16);
}

__device__ __forceinline__ unsigned short f2h(float f) {
  _Float16 h = (_Float16)f;
  return __builtin_bit_cast(unsigned short, h);
}

__device__ __forceinline__ void async16(const void* g, void* l) {
  __builtin_amdgcn_global_load_lds(
      (const __attribute__((address_space(1))) unsigned int*)g,
      (__attribute__((address_space(3))) unsigned int*)l, 16, 0, 0);
}

#define MFMA(a, b, c) __builtin_amdgcn_mfma_f32_16x16x32_bf16((a), (b), (c), 0, 0, 0)

// ---------------------------------------------------------------------------
// pack: fp32 -> bf16 (RNE), vectorized
// ---------------------------------------------------------------------------
__global__ __launch_bounds__(256) void pack_bf16(const float* __restrict__ src,
                                                 unsigned short* __restrict__ dst,
                                                 long n) {
  long i = ((long)blockIdx.x * blockDim.x + threadIdx.x) * 4;
  long stride = (long)gridDim.x * blockDim.x * 4;
  for (; i < n; i += stride) {
    float4 v = *(const float4*)(src + i);
    ushort4 o;
    o.x = f2bf(v.x); o.y = f2bf(v.y); o.z = f2bf(v.z); o.w = f2bf(v.w);
    *(ushort4*)(dst + i) = o;
  }
}

// ---------------------------------------------------------------------------
// gemm256: C[M,N] = A[M,K] * B[N,K]^T  (row-major bf16, K contiguous)
// 256x256 tile, BK=64, 8 waves (2Mx4N), 8-phase schedule (T2+T3+T4+T5):
//  - LDS 128KB dynamic: 2 buffers x {A0,A1,B0,B1} 16KB half-tiles, XOR swizzle
//    (byte ^= (row&7)<<4), global_load_lds w/ inverse-swizzled source.
//  - per K-tile: 4 phases x {ds_reads, stage 1 half-tile, bar, 16 MFMA, bar}.
//    A(t+1) staged phases 0/1 into buf^1; B(t+2) phases 2/3 into buf (slots
//    freed after phase 0). Counted s_waitcnt vmcnt(4) once per tile, before
//    the closing barrier (per-wave wait + barrier => block-wide guarantee).
// EPI 0: bf16 + bias into QKV; EPI 1: fp32*scale direct; EPI 2: fp16*scale.
// ---------------------------------------------------------------------------
template <int EPI>
__global__ __launch_bounds__(512, 2) void gemm256(
    const unsigned short* __restrict__ A, long sAz,
    const unsigned short* __restrict__ B, long sBz,
    int lda, int ldb, int nt,
    float* __restrict__ Cf, long sCz, int ldc, float scale,
    unsigned short* __restrict__ Cq, long sQz, int ldq,
    const float* __restrict__ bq, const float* __restrict__ bk,
    const float* __restrict__ bv) {
  extern __shared__ __align__(16) char smem[];
  const int tid = threadIdx.x;
  const int l = tid & 63;
  const int w = tid >> 6;
  const int wm = w >> 2, wn = w & 3;
  int bm = blockIdx.x;
  if ((gridDim.x & 7) == 0) {  // XCD-aware swizzle (bijective: gx % 8 == 0)
    int cpx = gridDim.x >> 3;
    bm = (bm & 7) * cpx + (bm >> 3);
  }
  const int bn = blockIdx.y, bz = blockIdx.z;
  const unsigned short* Ab = A + (long)bz * sAz + (long)bm * 256 * lda;
  const unsigned short* Bb = B + (long)bz * sBz + (long)bn * 256 * ldb;

  const int r0 = tid >> 3;                 // staging row 0..63
  const int sch = (tid & 7) ^ (r0 & 7);    // inverse-swizzled source chunk
  const int l15 = l & 15;
  const int kof = (l >> 4) << 3;           // 0,8,16,24

  const int aslot = wm * 16384;                     // A half used by this wave
  const int bslot = 32768 + (wn >> 1) * 16384;      // B half used by this wave
  const int brow0 = (wn & 1) * 64;

  f32x4 acc[8][4] = {};
  bf16x8 bfr[4][2];

#define LDA_FRAG(dst, buf, fr, ks)                                   \
  {                                                                  \
    int rins = (fr) * 16 + l15;                                      \
    int byte = (buf) + aslot + rins * 128 + ((ks) * 32 + kof) * 2;   \
    byte ^= (rins & 7) << 4;                                         \
    dst = *(const bf16x8*)(smem + byte);                             \
  }
#define LDB_FRAG(dst, buf, fc, ks)                                   \
  {                                                                  \
    int rins = brow0 + (fc) * 16 + l15;                              \
    int byte = (buf) + bslot + rins * 128 + ((ks) * 32 + kof) * 2;   \
    byte ^= (rins & 7) << 4;                                         \
    dst = *(const bf16x8*)(smem + byte);                             \
  }
#define STAGE_A(half, kt, dst)                                                  \
  {                                                                             \
    const unsigned short* s_ =                                                  \
        Ab + (long)((half) * 128 + r0) * lda + (kt) * 64 + sch * 8;             \
    async16(s_, smem + (dst) + tid * 16);                                       \
    async16(s_ + (long)64 * lda, smem + (dst) + 8192 + tid * 16);               \
  }
#define STAGE_B(half, kt, dst)                                                  \
  {                                                                             \
    const unsigned short* s_ =                                                  \
        Bb + (long)((half) * 128 + r0) * ldb + (kt) * 64 + sch * 8;             \
    async16(s_, smem + (dst) + tid * 16);                                       \
    async16(s_ + (long)64 * ldb, smem + (dst) + 8192 + tid * 16);               \
  }

  // prologue staging: B0(0) B1(0) A0(0) A1(0) B0(1) B1(1); allow last 2 halves
  STAGE_B(0, 0, 32768); STAGE_B(1, 0, 49152);
  STAGE_A(0, 0, 0);     STAGE_A(1, 0, 16384);
  STAGE_B(0, 1, 65536 + 32768); STAGE_B(1, 1, 65536 + 49152);
  asm volatile("s_waitcnt vmcnt(4)" ::: "memory");
  __builtin_amdgcn_s_barrier();

  for (int t = 0; t < nt; ++t) {
    const int buf = (t & 1) << 16;
    const int nbuf = buf ^ 65536;
    const int tA = (t + 1 < nt) ? t + 1 : nt - 1;  // clamped tail re-reads
    const int tB = (t + 2 < nt) ? t + 2 : nt - 1;

    bf16x8 a00, a01, a10, a11;

    // ---- phase 0: A fr{0,1} + B all; stage A0(t+1) -> buf^1
    LDA_FRAG(a00, buf, 0, 0); LDA_FRAG(a01, buf, 0, 1);
    LDA_FRAG(a10, buf, 1, 0); LDA_FRAG(a11, buf, 1, 1);
#pragma unroll
    for (int fc = 0; fc < 4; ++fc) {
      LDB_FRAG(bfr[fc][0], buf, fc, 0);
      LDB_FRAG(bfr[fc][1], buf, fc, 1);
    }
    STAGE_A(0, tA, nbuf);
    __builtin_amdgcn_s_barrier();
    __builtin_amdgcn_s_setprio(1);
#pragma unroll
    for (int fc = 0; fc < 4; ++fc) {
      acc[0][fc] = MFMA(a00, bfr[fc][0], acc[0][fc]);
      acc[0][fc] = MFMA(a01, bfr[fc][1], acc[0][fc]);
      acc[1][fc] = MFMA(a10, bfr[fc][0], acc[1][fc]);
      acc[1][fc] = MFMA(a11, bfr[fc][1], acc[1][fc]);
    }
    __builtin_amdgcn_s_setprio(0);
    __builtin_amdgcn_s_barrier();

    // ---- phase 1: A fr{2,3}; stage A1(t+1) -> buf^1
    LDA_FRAG(a00, buf, 2, 0); LDA_FRAG(a01, buf, 2, 1);
    LDA_FRAG(a10, buf, 3, 0); LDA_FRAG(a11, buf, 3, 1);
    STAGE_A(1, tA, nbuf + 16384);
    __builtin_amdgcn_s_barrier();
    __builtin_amdgcn_s_setprio(1);
#pragma unroll
    for (int fc = 0; fc < 4; ++fc) {
      acc[2][fc] = MFMA(a00, bfr[fc][0], acc[2][fc]);
      acc[2][fc] = MFMA(a01, bfr[fc][1], acc[2][fc]);
      acc[3][fc] = MFMA(a10, bfr[fc][0], acc[3][fc]);
      acc[3][fc] = MFMA(a11, bfr[fc][1], acc[3][fc]);
    }
    __builtin_amdgcn_s_setprio(0);
    __builtin_amdgcn_s_barrier();

    // ---- phase 2: A fr{4,5}; stage B0(t+2) -> buf (slot freed after phase 0)
    LDA_FRAG(a00, buf, 4, 0); LDA_FRAG(a01, buf, 4, 1);
    LDA_FRAG(a10, buf, 5, 0); LDA_FRAG(a11, buf, 5, 1);
    STAGE_B(0, tB, buf + 32768);
    __builtin_amdgcn_s_barrier();
    __builtin_amdgcn_s_setprio(1);
#pragma unroll
    for (int fc = 0; fc < 4; ++fc) {
      acc[4][fc] = MFMA(a00, bfr[fc][0], acc[4][fc]);
      acc[4][fc] = MFMA(a01, bfr[fc][1], acc[4][fc]);
      acc[5][fc] = MFMA(a10, bfr[fc][0], acc[5][fc]);
      acc[5][fc] = MFMA(a11, bfr[fc][1], acc[5][fc]);
    }
    __builtin_amdgcn_s_setprio(0);
    __builtin_amdgcn_s_barrier();

    // ---- phase 3: A fr{6,7}; stage B1(t+2) -> buf; counted vmcnt + barrier
    LDA_FRAG(a00, buf, 6, 0); LDA_FRAG(a01, buf, 6, 1);
    LDA_FRAG(a10, buf, 7, 0); LDA_FRAG(a11, buf, 7, 1);
    STAGE_B(1, tB, buf + 49152);
    __builtin_amdgcn_s_barrier();
    __builtin_amdgcn_s_setprio(1);
#pragma unroll
    for (int fc = 0; fc < 4; ++fc) {
      acc[6][fc] = MFMA(a00, bfr[fc][0], acc[6][fc]);
      acc[6][fc] = MFMA(a01, bfr[fc][1], acc[6][fc]);
      acc[7][fc] = MFMA(a10, bfr[fc][0], acc[7][fc]);
      acc[7][fc] = MFMA(a11, bfr[fc][1], acc[7][fc]);
    }
    __builtin_amdgcn_s_setprio(0);
    asm volatile("s_waitcnt vmcnt(4)" ::: "memory");
    __builtin_amdgcn_s_barrier();
  }

  // epilogue: drain staging queue before reusing LDS
  asm volatile("s_waitcnt vmcnt(0)" ::: "memory");
  __builtin_amdgcn_s_barrier();

  const int rl = (l >> 4) * 4;  // C/D layout: col=lane&15, row=(lane>>4)*4+reg

  if constexpr (EPI == 1) {
    float* C = Cf + (long)bz * sCz;
    const long grbase = (long)bm * 256 + wm * 128;
    const int gcbase = bn * 256 + wn * 64;
#pragma unroll
    for (int fr = 0; fr < 8; ++fr)
#pragma unroll
      for (int rr = 0; rr < 4; ++rr) {
        long gr = grbase + fr * 16 + rl + rr;
#pragma unroll
        for (int fc = 0; fc < 4; ++fc)
          C[gr * ldc + gcbase + fc * 16 + l15] = acc[fr][fc][rr] * scale;
      }
  } else {
    const int colbase = bn * 256 + wn * 64;
    const float* bias = nullptr;
    if constexpr (EPI == 0) {
      int which = colbase >> 10;
      bias = (which == 0) ? bq : (which == 1) ? bk : bv;
    }
#pragma unroll
    for (int fr = 0; fr < 8; ++fr)
#pragma unroll
      for (int fc = 0; fc < 4; ++fc) {
        int lc = fc * 16 + l15;
        float bv_ = 0.0f;
        if constexpr (EPI == 0) bv_ = bias[(colbase + lc) & 1023];
#pragma unroll
        for (int rr = 0; rr < 4; ++rr) {
          int lr = fr * 16 + rl + rr;
          int byte = w * 16384 + lr * 128 + lc * 2;
          byte ^= (lr & 7) << 4;
          unsigned short q;
          if constexpr (EPI == 0) q = f2bf(acc[fr][fc][rr] + bv_);
          else                    q = f2h(acc[fr][fc][rr] * scale);
          *(unsigned short*)(smem + byte) = q;
        }
      }
    __syncthreads();
    const long brow = (long)bm * 256;
#pragma unroll
    for (int it = 0; it < 16; ++it) {
      int f = it * 512 + tid;
      int r = f >> 5, ch = f & 31;
      int wv = (r >> 7) * 4 + (ch >> 3);
      int byte = wv * 16384 + (r & 127) * 128 + (ch & 7) * 16;
      byte ^= (r & 7) << 4;
      uint4 val = *(const uint4*)(smem + byte);
      if constexpr (EPI == 0) {
        int which = (bn * 256) >> 10;
        int cw0 = (bn * 256) & 1023;
        unsigned short* d = Cq + (long)which * 16777216L +
                            (brow + r) * 1024 + cw0 + ch * 8;
        *(uint4*)d = val;
      } else {
        unsigned short* d = Cq + (long)bz * sQz + (brow + r) * ldq +
                            bn * 256 + ch * 8;
        *(uint4*)d = val;
      }
    }
  }
#undef LDA_FRAG
#undef LDB_FRAG
#undef STAGE_A
#undef STAGE_B
}

// ---------------------------------------------------------------------------
// transpose V: [B,2048,1024] bf16 -> [B,1024,2048] bf16, 64x64 LDS tiles
// ---------------------------------------------------------------------------
__global__ __launch_bounds__(256) void transpose64(
    const unsigned short* __restrict__ V, unsigned short* __restrict__ Vt) {
  __shared__ unsigned short t[64][68];
  int b = blockIdx.z;
  int s0 = blockIdx.x * 64, d0 = blockIdx.y * 64;
  const unsigned short* src = V + (long)b * 2048 * 1024;
  unsigned short* dst = Vt + (long)b * 1024 * 2048;
  int r = threadIdx.x >> 4, c = threadIdx.x & 15;
#pragma unroll
  for (int i = 0; i < 4; ++i) {
    int row = i * 16 + r;
    const ushort2* p = (const ushort2*)(src + (long)(s0 + row) * 1024 + d0 + c * 4);
    ushort2 v0 = p[0], v1 = p[1];
    t[row][c * 4 + 0] = v0.x; t[row][c * 4 + 1] = v0.y;
    t[row][c * 4 + 2] = v1.x; t[row][c * 4 + 3] = v1.y;
  }
  __syncthreads();
#pragma unroll
  for (int i = 0; i < 4; ++i) {
    int drow = i * 16 + r;
    ushort2 o0, o1;
    o0.x = t[c * 4 + 0][drow]; o0.y = t[c * 4 + 1][drow];
    o1.x = t[c * 4 + 2][drow]; o1.y = t[c * 4 + 3][drow];
    ushort2* q = (ushort2*)(dst + (long)(d0 + drow) * 2048 + s0 + c * 4);
    q[0] = o0; q[1] = o1;
  }
}

// ---------------------------------------------------------------------------
// row softmax: fp16 scores [nrows x 2048] -> bf16 weights [nrows x 2048]
// ---------------------------------------------------------------------------
__global__ __launch_bounds__(256) void softmax_rows_h(
    const unsigned short* __restrict__ S, unsigned short* __restrict__ W) {
  long row = blockIdx.x;
  int t = threadIdx.x;
  f16x8v hv = *(const f16x8v*)(S + row * 2048 + t * 8);
  float v[8];
#pragma unroll
  for (int k = 0; k < 8; ++k) v[k] = (float)hv[k];
  float m = v[0];
#pragma unroll
  for (int k = 1; k < 8; ++k) m = fmaxf(m, v[k]);
#pragma unroll
  for (int o = 32; o; o >>= 1) m = fmaxf(m, __shfl_xor(m, o));
  __shared__ float redm[4];
  __shared__ float reds[4];
  int wv = t >> 6;
  if ((t & 63) == 0) redm[wv] = m;
  __syncthreads();
  m = fmaxf(fmaxf(redm[0], redm[1]), fmaxf(redm[2], redm[3]));
  float e[8], s = 0.0f;
#pragma unroll
  for (int k = 0; k < 8; ++k) { e[k] = __expf(v[k] - m); s += e[k]; }
#pragma unroll
  for (int o = 32; o; o >>= 1) s += __shfl_xor(s, o);
  if ((t & 63) == 0) reds[wv] = s;
  __syncthreads();
  s = reds[0] + reds[1] + reds[2] + reds[3];
  float inv = 1.0f / s;
  u16x8 o;
#pragma unroll
  for (int k = 0; k < 8; ++k) o[k] = f2bf(e[k] * inv);
  *(u16x8*)(W + row * 2048 + t * 8) = o;
}

__global__ void sentinel_kernel(float* out, float v) { out[0] = v; }

// ---------------------------------------------------------------------------
extern "C" void kernel_launch(void* const* d_in, const int* in_sizes, int n_in,
                              void* d_out, int out_size, void* d_ws, size_t ws_size,
                              hipStream_t stream) {
  const float* x  = (const float*)d_in[0];
  const float* Wq = (const float*)d_in[1];
  const float* bq = (const float*)d_in[2];
  const float* Wk = (const float*)d_in[3];
  const float* bk = (const float*)d_in[4];
  const float* Wv = (const float*)d_in[5];
  const float* bv = (const float*)d_in[6];
  float* out = (float*)d_out;

  // enable 128KB dynamic LDS for the 3 gemm256 instantiations (idempotent)
  (void)hipFuncSetAttribute((const void*)gemm256<0>,
      hipFuncAttributeMaxDynamicSharedMemorySize, 131072);
  (void)hipFuncSetAttribute((const void*)gemm256<1>,
      hipFuncAttributeMaxDynamicSharedMemorySize, 131072);
  (void)hipFuncSetAttribute((const void*)gemm256<2>,
      hipFuncAttributeMaxDynamicSharedMemorySize, 131072);

  // Tiers (chosen by ws_size, constant across calls):
  //  BIG (>=207618048): z=8 single-pass attention.
  //  MID (>=140509184): 4 passes x z=2 (round-3-verified layout).
  const size_t NEED_BIG = 207618048;
  const size_t NEED_MID = 140509184;
  if (ws_size < NEED_MID) {
    sentinel_kernel<<<1, 1, 0, stream>>>(out, (float)ws_size);
    return;
  }
  const bool big = (ws_size >= NEED_BIG);
  char* ws = (char*)d_ws;
  unsigned short* qkv = (unsigned short*)(ws);
  unsigned short* vt  = (unsigned short*)(ws + 100663296);
  unsigned short* wb  = (unsigned short*)(ws + 134217728);
  unsigned short* xb  = big ? (unsigned short*)(ws + 140509184)
                            : (unsigned short*)(ws + 100663296);
  unsigned short* sc  = big ? (unsigned short*)(ws + 140509184)
                            : (unsigned short*)(ws + 67108864);
  unsigned short* wt  = big ? (unsigned short*)(ws)
                            : (unsigned short*)(ws + 83886080);

  const float scale = 0.03125f;  // 1/sqrt(1024)

  pack_bf16<<<dim3(4096), dim3(256), 0, stream>>>(x, xb, 16777216L);
  pack_bf16<<<dim3(1024), dim3(256), 0, stream>>>(Wq, wb, 1048576L);
  pack_bf16<<<dim3(1024), dim3(256), 0, stream>>>(Wk, wb + 1048576, 1048576L);
  pack_bf16<<<dim3(1024), dim3(256), 0, stream>>>(Wv, wb + 2097152, 1048576L);

  // QKV projection: [16384,1024] x [3072,1024]^T -> qkv bf16 (+bias)
  gemm256<0><<<dim3(64, 12, 1), dim3(512), 131072, stream>>>(
      xb, 0L, wb, 0L, 1024, 1024, 16,
      nullptr, 0L, 0, 1.0f, qkv, 0L, 1024, bq, bk, bv);

  // V^T per batch (vt overwrites dead-xb region)
  transpose64<<<dim3(32, 16, 8), dim3(256), 0, stream>>>(qkv + 2L * 16777216, vt);

  const int bpp = big ? 8 : 2;        // batches per pass
  const int npasses = 8 / bpp;
  for (int p = 0; p < npasses; ++p) {
    long b0 = (long)p * bpp;
    long boff = b0 * 2048 * 1024;
    // scores = Q K^T * scale -> fp16 sc
    gemm256<2><<<dim3(8, 8, bpp), dim3(512), 131072, stream>>>(
        qkv + boff, 2048L * 1024, qkv + 16777216 + boff, 2048L * 1024,
        1024, 1024, 16,
        nullptr, 0L, 0, scale, sc, 2048L * 2048, 2048,
        nullptr, nullptr, nullptr);

    // softmax rows -> bf16 weights
    softmax_rows_h<<<dim3(2048 * bpp), dim3(256), 0, stream>>>(sc, wt);

    // out = weights @ V^T-rows -> fp32
    gemm256<1><<<dim3(8, 4, bpp), dim3(512), 131072, stream>>>(
        wt, 2048L * 2048, vt + b0 * 1024 * 2048, 1024L * 2048,
        2048, 2048, 32,
        out + boff, 2048L * 1024, 1024, 1.0f, nullptr, 0L, 0,
        nullptr, nullptr, nullptr);
  }
}

// Round 6
// 291.763 us; speedup vs baseline: 1.6281x; 1.1215x over previous
//
#include <hip/hip_runtime.h>

typedef __bf16 bf16x8 __attribute__((ext_vector_type(8)));
typedef float f32x4 __attribute__((ext_vector_type(4)));

__device__ __forceinline__ unsigned short f2bf(float f) {
  unsigned int u = __builtin_bit_cast(unsigned int, f);
  u += 0x7fffu + ((u >> 16) & 1u);
  return (unsigned short)(u >> 16);
}

__device__ __forceinline__ void async16(const void* g, void* l) {
  __builtin_amdgcn_global_load_lds(
      (const __attribute__((address_space(1))) unsigned int*)g,
      (__attribute__((address_space(3))) unsigned int*)l, 16, 0, 0);
}

#define MFMA(a, b, c) __builtin_amdgcn_mfma_f32_16x16x32_bf16((a), (b), (c), 0, 0, 0)

// ---------------------------------------------------------------------------
// pack: fp32 -> bf16 (RNE), vectorized
// ---------------------------------------------------------------------------
__global__ __launch_bounds__(256) void pack_bf16(const float* __restrict__ src,
                                                 unsigned short* __restrict__ dst,
                                                 long n) {
  long i = ((long)blockIdx.x * blockDim.x + threadIdx.x) * 4;
  long stride = (long)gridDim.x * blockDim.x * 4;
  for (; i < n; i += stride) {
    float4 v = *(const float4*)(src + i);
    ushort4 o;
    o.x = f2bf(v.x); o.y = f2bf(v.y); o.z = f2bf(v.z); o.w = f2bf(v.w);
    *(ushort4*)(dst + i) = o;
  }
}

// ---------------------------------------------------------------------------
// gemm256: C[M,N] = A[M,K] * B[N,K]^T  (row-major bf16, K contiguous)
// 256x256 tile, BK=64, 8 waves (2Mx4N), 8-phase schedule (T2+T3+T4+T5).
// K-loop identical to round-5 (validated). Epilogues:
//  EPI 0: QKV: bf16+bias; Q/K row-major; V written TRANSPOSED (V^T[b][d][s]).
//  EPI 3: scores: bf16 exp(s*scale) weights + per-(row,bn) partial sums.
//  EPI 4: PV: fp32 out * rsum[row] (reciprocal of weight-row sum).
// ---------------------------------------------------------------------------
template <int EPI>
__global__ __launch_bounds__(512, 2) void gemm256(
    const unsigned short* __restrict__ A, long sAz,
    const unsigned short* __restrict__ B, long sBz,
    int lda, int ldb, int nt,
    float* __restrict__ Cf, long sCz, int ldc, float scale,
    unsigned short* __restrict__ Cq, long sQz, int ldq,
    const float* __restrict__ bq, const float* __restrict__ bk,
    const float* __restrict__ bv,
    float* __restrict__ psum, const float* __restrict__ rsum) {
  extern __shared__ __align__(16) char smem[];
  const int tid = threadIdx.x;
  const int l = tid & 63;
  const int w = tid >> 6;
  const int wm = w >> 2, wn = w & 3;
  int bm = blockIdx.x;
  if ((gridDim.x & 7) == 0) {  // XCD-aware swizzle (identity when gx==8)
    int cpx = gridDim.x >> 3;
    bm = (bm & 7) * cpx + (bm >> 3);
  }
  const int bn = blockIdx.y, bz = blockIdx.z;
  const unsigned short* Ab = A + (long)bz * sAz + (long)bm * 256 * lda;
  const unsigned short* Bb = B + (long)bz * sBz + (long)bn * 256 * ldb;

  const int r0 = tid >> 3;                 // staging row 0..63
  const int sch = (tid & 7) ^ (r0 & 7);    // inverse-swizzled source chunk
  const int l15 = l & 15;
  const int kof = (l >> 4) << 3;           // 0,8,16,24

  const int aslot = wm * 16384;
  const int bslot = 32768 + (wn >> 1) * 16384;
  const int brow0 = (wn & 1) * 64;

  f32x4 acc[8][4] = {};
  bf16x8 bfr[4][2];

#define LDA_FRAG(dst, buf, fr, ks)                                   \
  {                                                                  \
    int rins = (fr) * 16 + l15;                                      \
    int byte = (buf) + aslot + rins * 128 + ((ks) * 32 + kof) * 2;   \
    byte ^= (rins & 7) << 4;                                         \
    dst = *(const bf16x8*)(smem + byte);                             \
  }
#define LDB_FRAG(dst, buf, fc, ks)                                   \
  {                                                                  \
    int rins = brow0 + (fc) * 16 + l15;                              \
    int byte = (buf) + bslot + rins * 128 + ((ks) * 32 + kof) * 2;   \
    byte ^= (rins & 7) << 4;                                         \
    dst = *(const bf16x8*)(smem + byte);                             \
  }
#define STAGE_A(half, kt, dst)                                                  \
  {                                                                             \
    const unsigned short* s_ =                                                  \
        Ab + (long)((half) * 128 + r0) * lda + (kt) * 64 + sch * 8;             \
    async16(s_, smem + (dst) + tid * 16);                                       \
    async16(s_ + (long)64 * lda, smem + (dst) + 8192 + tid * 16);               \
  }
#define STAGE_B(half, kt, dst)                                                  \
  {                                                                             \
    const unsigned short* s_ =                                                  \
        Bb + (long)((half) * 128 + r0) * ldb + (kt) * 64 + sch * 8;             \
    async16(s_, smem + (dst) + tid * 16);                                       \
    async16(s_ + (long)64 * ldb, smem + (dst) + 8192 + tid * 16);               \
  }

  // prologue staging: B0(0) B1(0) A0(0) A1(0) B0(1) B1(1)
  STAGE_B(0, 0, 32768); STAGE_B(1, 0, 49152);
  STAGE_A(0, 0, 0);     STAGE_A(1, 0, 16384);
  STAGE_B(0, 1, 65536 + 32768); STAGE_B(1, 1, 65536 + 49152);
  asm volatile("s_waitcnt vmcnt(4)" ::: "memory");
  __builtin_amdgcn_s_barrier();

  for (int t = 0; t < nt; ++t) {
    const int buf = (t & 1) << 16;
    const int nbuf = buf ^ 65536;
    const int tA = (t + 1 < nt) ? t + 1 : nt - 1;
    const int tB = (t + 2 < nt) ? t + 2 : nt - 1;

    bf16x8 a00, a01, a10, a11;

    // ---- phase 0
    LDA_FRAG(a00, buf, 0, 0); LDA_FRAG(a01, buf, 0, 1);
    LDA_FRAG(a10, buf, 1, 0); LDA_FRAG(a11, buf, 1, 1);
#pragma unroll
    for (int fc = 0; fc < 4; ++fc) {
      LDB_FRAG(bfr[fc][0], buf, fc, 0);
      LDB_FRAG(bfr[fc][1], buf, fc, 1);
    }
    STAGE_A(0, tA, nbuf);
    __builtin_amdgcn_s_barrier();
    __builtin_amdgcn_s_setprio(1);
#pragma unroll
    for (int fc = 0; fc < 4; ++fc) {
      acc[0][fc] = MFMA(a00, bfr[fc][0], acc[0][fc]);
      acc[0][fc] = MFMA(a01, bfr[fc][1], acc[0][fc]);
      acc[1][fc] = MFMA(a10, bfr[fc][0], acc[1][fc]);
      acc[1][fc] = MFMA(a11, bfr[fc][1], acc[1][fc]);
    }
    __builtin_amdgcn_s_setprio(0);
    __builtin_amdgcn_s_barrier();

    // ---- phase 1
    LDA_FRAG(a00, buf, 2, 0); LDA_FRAG(a01, buf, 2, 1);
    LDA_FRAG(a10, buf, 3, 0); LDA_FRAG(a11, buf, 3, 1);
    STAGE_A(1, tA, nbuf + 16384);
    __builtin_amdgcn_s_barrier();
    __builtin_amdgcn_s_setprio(1);
#pragma unroll
    for (int fc = 0; fc < 4; ++fc) {
      acc[2][fc] = MFMA(a00, bfr[fc][0], acc[2][fc]);
      acc[2][fc] = MFMA(a01, bfr[fc][1], acc[2][fc]);
      acc[3][fc] = MFMA(a10, bfr[fc][0], acc[3][fc]);
      acc[3][fc] = MFMA(a11, bfr[fc][1], acc[3][fc]);
    }
    __builtin_amdgcn_s_setprio(0);
    __builtin_amdgcn_s_barrier();

    // ---- phase 2
    LDA_FRAG(a00, buf, 4, 0); LDA_FRAG(a01, buf, 4, 1);
    LDA_FRAG(a10, buf, 5, 0); LDA_FRAG(a11, buf, 5, 1);
    STAGE_B(0, tB, buf + 32768);
    __builtin_amdgcn_s_barrier();
    __builtin_amdgcn_s_setprio(1);
#pragma unroll
    for (int fc = 0; fc < 4; ++fc) {
      acc[4][fc] = MFMA(a00, bfr[fc][0], acc[4][fc]);
      acc[4][fc] = MFMA(a01, bfr[fc][1], acc[4][fc]);
      acc[5][fc] = MFMA(a10, bfr[fc][0], acc[5][fc]);
      acc[5][fc] = MFMA(a11, bfr[fc][1], acc[5][fc]);
    }
    __builtin_amdgcn_s_setprio(0);
    __builtin_amdgcn_s_barrier();

    // ---- phase 3
    LDA_FRAG(a00, buf, 6, 0); LDA_FRAG(a01, buf, 6, 1);
    LDA_FRAG(a10, buf, 7, 0); LDA_FRAG(a11, buf, 7, 1);
    STAGE_B(1, tB, buf + 49152);
    __builtin_amdgcn_s_barrier();
    __builtin_amdgcn_s_setprio(1);
#pragma unroll
    for (int fc = 0; fc < 4; ++fc) {
      acc[6][fc] = MFMA(a00, bfr[fc][0], acc[6][fc]);
      acc[6][fc] = MFMA(a01, bfr[fc][1], acc[6][fc]);
      acc[7][fc] = MFMA(a10, bfr[fc][0], acc[7][fc]);
      acc[7][fc] = MFMA(a11, bfr[fc][1], acc[7][fc]);
    }
    __builtin_amdgcn_s_setprio(0);
    asm volatile("s_waitcnt vmcnt(4)" ::: "memory");
    __builtin_amdgcn_s_barrier();
  }

  asm volatile("s_waitcnt vmcnt(0)" ::: "memory");
  __builtin_amdgcn_s_barrier();

  const int rl = (l >> 4) * 4;  // C/D layout: col=lane&15, row=(lane>>4)*4+reg

  if constexpr (EPI == 0) {
    const int which = (bn * 256) >> 10;      // 0=Q 1=K 2=V
    const int colbase = bn * 256 + wn * 64;
    const float* bias = (which == 0) ? bq : (which == 1) ? bk : bv;
    if (which < 2) {
      // row-major staging + coalesced readout
#pragma unroll
      for (int fr = 0; fr < 8; ++fr)
#pragma unroll
        for (int fc = 0; fc < 4; ++fc) {
          int lc = fc * 16 + l15;
          float bv_ = bias[(colbase + lc) & 1023];
#pragma unroll
          for (int rr = 0; rr < 4; ++rr) {
            int lr = fr * 16 + rl + rr;
            int byte = w * 16384 + lr * 128 + lc * 2;
            byte ^= (lr & 7) << 4;
            *(unsigned short*)(smem + byte) = f2bf(acc[fr][fc][rr] + bv_);
          }
        }
      __syncthreads();
      const long brow = (long)bm * 256;
      const int cw0 = (bn * 256) & 1023;
#pragma unroll
      for (int it = 0; it < 16; ++it) {
        int f = it * 512 + tid;
        int r = f >> 5, ch = f & 31;
        int wv = (r >> 7) * 4 + (ch >> 3);
        int byte = wv * 16384 + (r & 127) * 128 + (ch & 7) * 16;
        byte ^= (r & 7) << 4;
        uint4 val = *(const uint4*)(smem + byte);
        unsigned short* d = Cq + (long)which * 16777216L +
                            (brow + r) * 1024 + cw0 + ch * 8;
        *(uint4*)d = val;
      }
    } else {
      // V: transposed staging [c][r] -> write V^T[b][d][s] coalesced
#pragma unroll
      for (int fr = 0; fr < 8; ++fr)
#pragma unroll
        for (int fc = 0; fc < 4; ++fc) {
          int lc = wn * 64 + fc * 16 + l15;    // tile col 0..255 (d)
          float bv_ = bias[(colbase + fc * 16 + l15) & 1023];
#pragma unroll
          for (int rr = 0; rr < 4; ++rr) {
            int r = wm * 128 + fr * 16 + rl + rr;  // tile row 0..255 (s)
            int byte = lc * 512 + r * 2;
            byte ^= (lc & 7) << 4;
            *(unsigned short*)(smem + byte) = f2bf(acc[fr][fc][rr] + bv_);
          }
        }
      __syncthreads();
      const long brow = (long)bm * 256;
      const long b = brow >> 11;               // batch
      const long s0 = brow & 2047;
      unsigned short* VT = Cq + 2L * 16777216;
#pragma unroll
      for (int it = 0; it < 16; ++it) {
        int f = it * 512 + tid;
        int c = f >> 5, ch = f & 31;
        int byte = (c * 512 + ch * 16) ^ ((c & 7) << 4);
        uint4 val = *(const uint4*)(smem + byte);
        int d = (bn * 256 - 2048) + c;
        unsigned short* dst = VT + b * 2097152 + (long)d * 2048 + s0 + ch * 8;
        *(uint4*)dst = val;
      }
    }
  } else if constexpr (EPI == 3) {
    // scores: w = exp(s*scale) -> bf16 staged; per-row partial sums
    float rs[4];
#pragma unroll
    for (int fr = 0; fr < 8; ++fr) {
      rs[0] = rs[1] = rs[2] = rs[3] = 0.0f;
#pragma unroll
      for (int fc = 0; fc < 4; ++fc) {
        int lc = fc * 16 + l15;
#pragma unroll
        for (int rr = 0; rr < 4; ++rr) {
          float e = __expf(acc[fr][fc][rr] * scale);
          rs[rr] += e;
          int lr = fr * 16 + rl + rr;
          int byte = w * 16384 + lr * 128 + lc * 2;
          byte ^= (lr & 7) << 4;
          *(unsigned short*)(smem + byte) = f2bf(e);
        }
      }
#pragma unroll
      for (int rr = 0; rr < 4; ++rr) {
        float v = rs[rr];
#pragma unroll
        for (int o = 1; o < 16; o <<= 1) v += __shfl_xor(v, o);
        if (l15 == 0) {
          int row = wm * 128 + fr * 16 + rl + rr;
          *(float*)(smem + 131072 + (wn * 256 + row) * 4) = v;
        }
      }
    }
    __syncthreads();
    const long brow = (long)bm * 256;
#pragma unroll
    for (int it = 0; it < 16; ++it) {
      int f = it * 512 + tid;
      int r = f >> 5, ch = f & 31;
      int wv = (r >> 7) * 4 + (ch >> 3);
      int byte = wv * 16384 + (r & 127) * 128 + (ch & 7) * 16;
      byte ^= (r & 7) << 4;
      uint4 val = *(const uint4*)(smem + byte);
      unsigned short* d = Cq + (long)bz * sQz + (brow + r) * ldq + bn * 256 + ch * 8;
      *(uint4*)d = val;
    }
    if (tid < 256) {
      float s4 = *(const float*)(smem + 131072 + tid * 4) +
                 *(const float*)(smem + 131072 + 1024 + tid * 4) +
                 *(const float*)(smem + 131072 + 2048 + tid * 4) +
                 *(const float*)(smem + 131072 + 3072 + tid * 4);
      psum[(((long)bz * 2048) + brow + tid) * 8 + bn] = s4;
    }
  } else {  // EPI == 4: PV, normalize by rsum (reciprocal)
    float* C = Cf + (long)bz * sCz;
    const float* rsb = rsum + (long)bz * 2048;
    const long grbase = (long)bm * 256 + wm * 128;
    const int gcbase = bn * 256 + wn * 64;
#pragma unroll
    for (int fr = 0; fr < 8; ++fr)
#pragma unroll
      for (int rr = 0; rr < 4; ++rr) {
        long gr = grbase + fr * 16 + rl + rr;
        float inv = rsb[gr];
#pragma unroll
        for (int fc = 0; fc < 4; ++fc)
          C[gr * ldc + gcbase + fc * 16 + l15] = acc[fr][fc][rr] * inv;
      }
  }
#undef LDA_FRAG
#undef LDB_FRAG
#undef STAGE_A
#undef STAGE_B
}

// ---------------------------------------------------------------------------
// reduce_psum: rsum[i] = 1 / sum_{j<8} psum[i][j]
// ---------------------------------------------------------------------------
__global__ __launch_bounds__(256) void reduce_psum(const float* __restrict__ p,
                                                   float* __restrict__ r, int n) {
  int i = blockIdx.x * 256 + threadIdx.x;
  if (i < n) {
    const float* q = p + (long)i * 8;
    float s = q[0] + q[1] + q[2] + q[3] + q[4] + q[5] + q[6] + q[7];
    r[i] = 1.0f / s;
  }
}

__global__ void sentinel_kernel(float* out, float v) { out[0] = v; }

// ---------------------------------------------------------------------------
extern "C" void kernel_launch(void* const* d_in, const int* in_sizes, int n_in,
                              void* d_out, int out_size, void* d_ws, size_t ws_size,
                              hipStream_t stream) {
  const float* x  = (const float*)d_in[0];
  const float* Wq = (const float*)d_in[1];
  const float* bq = (const float*)d_in[2];
  const float* Wk = (const float*)d_in[3];
  const float* bk = (const float*)d_in[4];
  const float* Wv = (const float*)d_in[5];
  const float* bv = (const float*)d_in[6];
  float* out = (float*)d_out;

  (void)hipFuncSetAttribute((const void*)gemm256<0>,
      hipFuncAttributeMaxDynamicSharedMemorySize, 135168);
  (void)hipFuncSetAttribute((const void*)gemm256<3>,
      hipFuncAttributeMaxDynamicSharedMemorySize, 135168);
  (void)hipFuncSetAttribute((const void*)gemm256<4>,
      hipFuncAttributeMaxDynamicSharedMemorySize, 135168);

  // Tiers (chosen by ws_size -> constant across calls):
  //  BIG2 (>=208207872): single-shot z=8.
  //    qkv[0,96M): Q[0,32M) K[32,64) VT[64,96)  (VT = V^T per batch [1024][2048])
  //    xb[96,128M) wb[128,134.2M)   (both dead after QKV gemm)
  //    wt[134.2M, 198.2M)  psum[198.2M,+512K)  rsum[+64K)
  //  SMALL2 (>=140509184): 4 passes x z=2; wt(16M)+psum+rsum inside dead xb.
  const size_t NEED_BIG2 = 208207872;
  const size_t NEED_SM2  = 140509184;
  if (ws_size < NEED_SM2) {
    sentinel_kernel<<<1, 1, 0, stream>>>(out, (float)ws_size);
    return;
  }
  const bool big = (ws_size >= NEED_BIG2);
  char* ws = (char*)d_ws;
  unsigned short* qkv = (unsigned short*)(ws);
  unsigned short* xb  = (unsigned short*)(ws + 100663296);
  unsigned short* wb  = (unsigned short*)(ws + 134217728);
  unsigned short* wt  = big ? (unsigned short*)(ws + 140509184)
                            : (unsigned short*)(ws + 100663296);
  float* psum = big ? (float*)(ws + 207618048) : (float*)(ws + 117440512);
  float* rsum = big ? (float*)(ws + 208142336) : (float*)(ws + 117571584);

  const float scale = 0.03125f;  // 1/sqrt(1024)

  pack_bf16<<<dim3(4096), dim3(256), 0, stream>>>(x, xb, 16777216L);
  pack_bf16<<<dim3(1024), dim3(256), 0, stream>>>(Wq, wb, 1048576L);
  pack_bf16<<<dim3(1024), dim3(256), 0, stream>>>(Wk, wb + 1048576, 1048576L);
  pack_bf16<<<dim3(1024), dim3(256), 0, stream>>>(Wv, wb + 2097152, 1048576L);

  // QKV projection: [16384,1024] x [3072,1024]^T -> Q,K row-major + V^T
  gemm256<0><<<dim3(64, 12, 1), dim3(512), 135168, stream>>>(
      xb, 0L, wb, 0L, 1024, 1024, 16,
      nullptr, 0L, 0, 1.0f, qkv, 0L, 1024, bq, bk, bv, nullptr, nullptr);

  const int bpp = big ? 8 : 2;
  const int npasses = 8 / bpp;
  for (int p = 0; p < npasses; ++p) {
    long b0 = (long)p * bpp;
    long boff = b0 * 2048 * 1024;
    // scores: exp(QK^T * scale) -> bf16 weights wt + psum partials
    gemm256<3><<<dim3(8, 8, bpp), dim3(512), 135168, stream>>>(
        qkv + boff, 2048L * 1024, qkv + 16777216 + boff, 2048L * 1024,
        1024, 1024, 16,
        nullptr, 0L, 0, scale, wt, 2048L * 2048, 2048,
        nullptr, nullptr, nullptr, psum, nullptr);

    // row-sum reciprocals
    reduce_psum<<<dim3(8 * bpp), dim3(256), 0, stream>>>(psum, rsum, 2048 * bpp);

    // out = (wt @ V^T-rows) * rsum : fp32
    gemm256<4><<<dim3(8, 4, bpp), dim3(512), 135168, stream>>>(
        wt, 2048L * 2048, qkv + 2L * 16777216 + b0 * 2097152, 2097152L,
        2048, 2048, 32,
        out + boff, 2048L * 1024, 1024, 1.0f, nullptr, 0L, 0,
        nullptr, nullptr, nullptr, nullptr, rsum);
  }
}

// Round 7
// 288.487 us; speedup vs baseline: 1.6465x; 1.0114x over previous
//
#include <hip/hip_runtime.h>

typedef __bf16 bf16x8 __attribute__((ext_vector_type(8)));
typedef float f32x4 __attribute__((ext_vector_type(4)));

__device__ __forceinline__ unsigned short f2bf(float f) {
  unsigned int u = __builtin_bit_cast(unsigned int, f);
  u += 0x7fffu + ((u >> 16) & 1u);
  return (unsigned short)(u >> 16);
}

__device__ __forceinline__ void async16(const void* g, void* l) {
  __builtin_amdgcn_global_load_lds(
      (const __attribute__((address_space(1))) unsigned int*)g,
      (__attribute__((address_space(3))) unsigned int*)l, 16, 0, 0);
}

#define MFMA(a, b, c) __builtin_amdgcn_mfma_f32_16x16x32_bf16((a), (b), (c), 0, 0, 0)

// ---------------------------------------------------------------------------
// pack: fp32 -> bf16 (RNE), vectorized
// ---------------------------------------------------------------------------
__global__ __launch_bounds__(256) void pack_bf16(const float* __restrict__ src,
                                                 unsigned short* __restrict__ dst,
                                                 long n) {
  long i = ((long)blockIdx.x * blockDim.x + threadIdx.x) * 4;
  long stride = (long)gridDim.x * blockDim.x * 4;
  for (; i < n; i += stride) {
    float4 v = *(const float4*)(src + i);
    ushort4 o;
    o.x = f2bf(v.x); o.y = f2bf(v.y); o.z = f2bf(v.z); o.w = f2bf(v.w);
    *(ushort4*)(dst + i) = o;
  }
}

// ---------------------------------------------------------------------------
// gemm256: C[M,N] = A[M,K] * B[N,K]^T  (row-major bf16, K contiguous)
// 256x256 tile, BK=64, 8 waves (2Mx4N), 8-phase schedule (T2+T3+T4+T5).
// Schedule identical to round-5/6 (validated). This round: strength-reduced
// addressing — 8 running global staging pointers (+64/tile, clamped to
// reproduce min(t+1,nt-1)/min(t+2,nt-1)) and precomputed swizzled LDS
// fragment offsets in registers. launch_bounds relaxed to (512,1): LDS
// already caps at 1 block/CU, so the VGPR cap was pure constraint.
//  EPI 0: QKV: bf16+bias; Q/K row-major; V written TRANSPOSED (V^T[b][d][s]).
//  EPI 3: scores: bf16 exp(s*scale) weights + per-(row,bn) partial sums.
//  EPI 4: PV: fp32 out * rsum[row] (reciprocal of weight-row sum).
// ---------------------------------------------------------------------------
template <int EPI>
__global__ __launch_bounds__(512, 1) void gemm256(
    const unsigned short* __restrict__ A, long sAz,
    const unsigned short* __restrict__ B, long sBz,
    int lda, int ldb, int nt,
    float* __restrict__ Cf, long sCz, int ldc, float scale,
    unsigned short* __restrict__ Cq, long sQz, int ldq,
    const float* __restrict__ bq, const float* __restrict__ bk,
    const float* __restrict__ bv,
    float* __restrict__ psum, const float* __restrict__ rsum) {
  extern __shared__ __align__(16) char smem[];
  const int tid = threadIdx.x;
  const int l = tid & 63;
  const int w = tid >> 6;
  const int wm = w >> 2, wn = w & 3;
  int bm = blockIdx.x;
  if ((gridDim.x & 7) == 0) {  // XCD-aware swizzle (identity when gx==8)
    int cpx = gridDim.x >> 3;
    bm = (bm & 7) * cpx + (bm >> 3);
  }
  const int bn = blockIdx.y, bz = blockIdx.z;
  const unsigned short* Ab = A + (long)bz * sAz + (long)bm * 256 * lda;
  const unsigned short* Bb = B + (long)bz * sBz + (long)bn * 256 * ldb;

  const int r0 = tid >> 3;                 // staging row 0..63
  const int sch = (tid & 7) ^ (r0 & 7);    // inverse-swizzled source chunk
  const int l15 = l & 15;
  const int kof = (l >> 4) << 3;           // 0,8,16,24

  const int aslot = wm * 16384;
  const int bslot = 32768 + (wn >> 1) * 16384;
  const int brow0 = (wn & 1) * 64;

  // precomputed swizzled LDS fragment byte offsets (add buf at use)
  int aof[8][2], bof[4][2];
#pragma unroll
  for (int fr = 0; fr < 8; ++fr)
#pragma unroll
    for (int ks = 0; ks < 2; ++ks) {
      int rins = fr * 16 + l15;
      int byte = aslot + rins * 128 + (ks * 32 + kof) * 2;
      aof[fr][ks] = byte ^ ((rins & 7) << 4);
    }
#pragma unroll
  for (int fc = 0; fc < 4; ++fc)
#pragma unroll
    for (int ks = 0; ks < 2; ++ks) {
      int rins = brow0 + fc * 16 + l15;
      int byte = bslot + rins * 128 + (ks * 32 + kof) * 2;
      bof[fc][ks] = byte ^ ((rins & 7) << 4);
    }

  // running staging pointers (one per 64-row group), +64 elems per tile
  const unsigned short* pa0 = Ab + (long)r0 * lda + sch * 8;
  const unsigned short* pa1 = pa0 + (long)64 * lda;
  const unsigned short* pa2 = pa0 + (long)128 * lda;
  const unsigned short* pa3 = pa0 + (long)192 * lda;
  const unsigned short* pb0 = Bb + (long)r0 * ldb + sch * 8;
  const unsigned short* pb1 = pb0 + (long)64 * ldb;
  const unsigned short* pb2 = pb0 + (long)128 * ldb;
  const unsigned short* pb3 = pb0 + (long)192 * ldb;

  char* sdst = smem + (tid << 4);  // LDS staging dest base (lane-linear)

  f32x4 acc[8][4] = {};
  bf16x8 bfr[4][2];

#define LDA_FRAG(dst, bb, fr, ks) \
  dst = *(const bf16x8*)(smem + (aof[fr][ks] + (bb)));
#define LDB_FRAG(dst, bb, fc, ks) \
  dst = *(const bf16x8*)(smem + (bof[fc][ks] + (bb)));

  // prologue staging (same issue order/counts as r6): B(0) A(0) B(1)
  async16(pb0, sdst + 32768);         async16(pb1, sdst + 40960);
  async16(pb2, sdst + 49152);         async16(pb3, sdst + 57344);
  async16(pa0, sdst + 0);             async16(pa1, sdst + 8192);
  async16(pa2, sdst + 16384);         async16(pa3, sdst + 24576);
  async16(pb0 + 64, sdst + 98304);    async16(pb1 + 64, sdst + 106496);
  async16(pb2 + 64, sdst + 114688);   async16(pb3 + 64, sdst + 122880);
  asm volatile("s_waitcnt vmcnt(4)" ::: "memory");
  __builtin_amdgcn_s_barrier();
  // advance: pa -> tile 1 (tA for t=0), pb -> tile 2 (tB for t=0)
  pa0 += 64; pa1 += 64; pa2 += 64; pa3 += 64;
  pb0 += 128; pb1 += 128; pb2 += 128; pb3 += 128;

  for (int t = 0; t < nt; ++t) {
    const int buf = (t & 1) << 16;
    const int nbuf = buf ^ 65536;

    bf16x8 a00, a01, a10, a11;

    // ---- phase 0: A fr{0,1}; all B; stage A half0(t+1) -> buf^1
    LDA_FRAG(a00, buf, 0, 0); LDA_FRAG(a01, buf, 0, 1);
    LDA_FRAG(a10, buf, 1, 0); LDA_FRAG(a11, buf, 1, 1);
#pragma unroll
    for (int fc = 0; fc < 4; ++fc) {
      LDB_FRAG(bfr[fc][0], buf, fc, 0);
      LDB_FRAG(bfr[fc][1], buf, fc, 1);
    }
    async16(pa0, sdst + nbuf);
    async16(pa1, sdst + nbuf + 8192);
    __builtin_amdgcn_s_barrier();
    __builtin_amdgcn_s_setprio(1);
#pragma unroll
    for (int fc = 0; fc < 4; ++fc) {
      acc[0][fc] = MFMA(a00, bfr[fc][0], acc[0][fc]);
      acc[0][fc] = MFMA(a01, bfr[fc][1], acc[0][fc]);
      acc[1][fc] = MFMA(a10, bfr[fc][0], acc[1][fc]);
      acc[1][fc] = MFMA(a11, bfr[fc][1], acc[1][fc]);
    }
    __builtin_amdgcn_s_setprio(0);
    __builtin_amdgcn_s_barrier();

    // ---- phase 1: A fr{2,3}; stage A half1(t+1) -> buf^1
    LDA_FRAG(a00, buf, 2, 0); LDA_FRAG(a01, buf, 2, 1);
    LDA_FRAG(a10, buf, 3, 0); LDA_FRAG(a11, buf, 3, 1);
    async16(pa2, sdst + nbuf + 16384);
    async16(pa3, sdst + nbuf + 24576);
    __builtin_amdgcn_s_barrier();
    __builtin_amdgcn_s_setprio(1);
#pragma unroll
    for (int fc = 0; fc < 4; ++fc) {
      acc[2][fc] = MFMA(a00, bfr[fc][0], acc[2][fc]);
      acc[2][fc] = MFMA(a01, bfr[fc][1], acc[2][fc]);
      acc[3][fc] = MFMA(a10, bfr[fc][0], acc[3][fc]);
      acc[3][fc] = MFMA(a11, bfr[fc][1], acc[3][fc]);
    }
    __builtin_amdgcn_s_setprio(0);
    __builtin_amdgcn_s_barrier();

    // ---- phase 2: A fr{4,5}; stage B half0(t+2) -> buf
    LDA_FRAG(a00, buf, 4, 0); LDA_FRAG(a01, buf, 4, 1);
    LDA_FRAG(a10, buf, 5, 0); LDA_FRAG(a11, buf, 5, 1);
    async16(pb0, sdst + buf + 32768);
    async16(pb1, sdst + buf + 40960);
    __builtin_amdgcn_s_barrier();
    __builtin_amdgcn_s_setprio(1);
#pragma unroll
    for (int fc = 0; fc < 4; ++fc) {
      acc[4][fc] = MFMA(a00, bfr[fc][0], acc[4][fc]);
      acc[4][fc] = MFMA(a01, bfr[fc][1], acc[4][fc]);
      acc[5][fc] = MFMA(a10, bfr[fc][0], acc[5][fc]);
      acc[5][fc] = MFMA(a11, bfr[fc][1], acc[5][fc]);
    }
    __builtin_amdgcn_s_setprio(0);
    __builtin_amdgcn_s_barrier();

    // ---- phase 3: A fr{6,7}; stage B half1(t+2) -> buf; vmcnt(4)+barrier
    LDA_FRAG(a00, buf, 6, 0); LDA_FRAG(a01, buf, 6, 1);
    LDA_FRAG(a10, buf, 7, 0); LDA_FRAG(a11, buf, 7, 1);
    async16(pb2, sdst + buf + 49152);
    async16(pb3, sdst + buf + 57344);
    __builtin_amdgcn_s_barrier();
    __builtin_amdgcn_s_setprio(1);
#pragma unroll
    for (int fc = 0; fc < 4; ++fc) {
      acc[6][fc] = MFMA(a00, bfr[fc][0], acc[6][fc]);
      acc[6][fc] = MFMA(a01, bfr[fc][1], acc[6][fc]);
      acc[7][fc] = MFMA(a10, bfr[fc][0], acc[7][fc]);
      acc[7][fc] = MFMA(a11, bfr[fc][1], acc[7][fc]);
    }
    __builtin_amdgcn_s_setprio(0);
    asm volatile("s_waitcnt vmcnt(4)" ::: "memory");
    __builtin_amdgcn_s_barrier();

    // pointer advance with clamp (reproduces r6's min(t+1,nt-1)/min(t+2,nt-1))
    if (t < nt - 2) { pa0 += 64; pa1 += 64; pa2 += 64; pa3 += 64; }
    if (t < nt - 3) { pb0 += 64; pb1 += 64; pb2 += 64; pb3 += 64; }
  }

  asm volatile("s_waitcnt vmcnt(0)" ::: "memory");
  __builtin_amdgcn_s_barrier();

  const int rl = (l >> 4) * 4;  // C/D layout: col=lane&15, row=(lane>>4)*4+reg

  if constexpr (EPI == 0) {
    const int which = (bn * 256) >> 10;      // 0=Q 1=K 2=V
    const int colbase = bn * 256 + wn * 64;
    const float* bias = (which == 0) ? bq : (which == 1) ? bk : bv;
    if (which < 2) {
      // row-major staging + coalesced readout
#pragma unroll
      for (int fr = 0; fr < 8; ++fr)
#pragma unroll
        for (int fc = 0; fc < 4; ++fc) {
          int lc = fc * 16 + l15;
          float bv_ = bias[(colbase + lc) & 1023];
#pragma unroll
          for (int rr = 0; rr < 4; ++rr) {
            int lr = fr * 16 + rl + rr;
            int byte = w * 16384 + lr * 128 + lc * 2;
            byte ^= (lr & 7) << 4;
            *(unsigned short*)(smem + byte) = f2bf(acc[fr][fc][rr] + bv_);
          }
        }
      __syncthreads();
      const long brow = (long)bm * 256;
      const int cw0 = (bn * 256) & 1023;
#pragma unroll
      for (int it = 0; it < 16; ++it) {
        int f = it * 512 + tid;
        int r = f >> 5, ch = f & 31;
        int wv = (r >> 7) * 4 + (ch >> 3);
        int byte = wv * 16384 + (r & 127) * 128 + (ch & 7) * 16;
        byte ^= (r & 7) << 4;
        uint4 val = *(const uint4*)(smem + byte);
        unsigned short* d = Cq + (long)which * 16777216L +
                            (brow + r) * 1024 + cw0 + ch * 8;
        *(uint4*)d = val;
      }
    } else {
      // V: transposed staging [c][r] -> write V^T[b][d][s] coalesced
#pragma unroll
      for (int fr = 0; fr < 8; ++fr)
#pragma unroll
        for (int fc = 0; fc < 4; ++fc) {
          int lc = wn * 64 + fc * 16 + l15;    // tile col 0..255 (d)
          float bv_ = bias[(colbase + fc * 16 + l15) & 1023];
#pragma unroll
          for (int rr = 0; rr < 4; ++rr) {
            int r = wm * 128 + fr * 16 + rl + rr;  // tile row 0..255 (s)
            int byte = lc * 512 + r * 2;
            byte ^= (lc & 7) << 4;
            *(unsigned short*)(smem + byte) = f2bf(acc[fr][fc][rr] + bv_);
          }
        }
      __syncthreads();
      const long brow = (long)bm * 256;
      const long b = brow >> 11;               // batch
      const long s0 = brow & 2047;
      unsigned short* VT = Cq + 2L * 16777216;
#pragma unroll
      for (int it = 0; it < 16; ++it) {
        int f = it * 512 + tid;
        int c = f >> 5, ch = f & 31;
        int byte = (c * 512 + ch * 16) ^ ((c & 7) << 4);
        uint4 val = *(const uint4*)(smem + byte);
        int d = (bn * 256 - 2048) + c;
        unsigned short* dst = VT + b * 2097152 + (long)d * 2048 + s0 + ch * 8;
        *(uint4*)dst = val;
      }
    }
  } else if constexpr (EPI == 3) {
    // scores: w = exp(s*scale) -> bf16 staged; per-row partial sums
    float rs[4];
#pragma unroll
    for (int fr = 0; fr < 8; ++fr) {
      rs[0] = rs[1] = rs[2] = rs[3] = 0.0f;
#pragma unroll
      for (int fc = 0; fc < 4; ++fc) {
        int lc = fc * 16 + l15;
#pragma unroll
        for (int rr = 0; rr < 4; ++rr) {
          float e = __expf(acc[fr][fc][rr] * scale);
          rs[rr] += e;
          int lr = fr * 16 + rl + rr;
          int byte = w * 16384 + lr * 128 + lc * 2;
          byte ^= (lr & 7) << 4;
          *(unsigned short*)(smem + byte) = f2bf(e);
        }
      }
#pragma unroll
      for (int rr = 0; rr < 4; ++rr) {
        float v = rs[rr];
#pragma unroll
        for (int o = 1; o < 16; o <<= 1) v += __shfl_xor(v, o);
        if (l15 == 0) {
          int row = wm * 128 + fr * 16 + rl + rr;
          *(float*)(smem + 131072 + (wn * 256 + row) * 4) = v;
        }
      }
    }
    __syncthreads();
    const long brow = (long)bm * 256;
#pragma unroll
    for (int it = 0; it < 16; ++it) {
      int f = it * 512 + tid;
      int r = f >> 5, ch = f & 31;
      int wv = (r >> 7) * 4 + (ch >> 3);
      int byte = wv * 16384 + (r & 127) * 128 + (ch & 7) * 16;
      byte ^= (r & 7) << 4;
      uint4 val = *(const uint4*)(smem + byte);
      unsigned short* d = Cq + (long)bz * sQz + (brow + r) * ldq + bn * 256 + ch * 8;
      *(uint4*)d = val;
    }
    if (tid < 256) {
      float s4 = *(const float*)(smem + 131072 + tid * 4) +
                 *(const float*)(smem + 131072 + 1024 + tid * 4) +
                 *(const float*)(smem + 131072 + 2048 + tid * 4) +
                 *(const float*)(smem + 131072 + 3072 + tid * 4);
      psum[(((long)bz * 2048) + brow + tid) * 8 + bn] = s4;
    }
  } else {  // EPI == 4: PV, normalize by rsum (reciprocal)
    float* C = Cf + (long)bz * sCz;
    const float* rsb = rsum + (long)bz * 2048;
    const long grbase = (long)bm * 256 + wm * 128;
    const int gcbase = bn * 256 + wn * 64;
#pragma unroll
    for (int fr = 0; fr < 8; ++fr)
#pragma unroll
      for (int rr = 0; rr < 4; ++rr) {
        long gr = grbase + fr * 16 + rl + rr;
        float inv = rsb[gr];
#pragma unroll
        for (int fc = 0; fc < 4; ++fc)
          C[gr * ldc + gcbase + fc * 16 + l15] = acc[fr][fc][rr] * inv;
      }
  }
#undef LDA_FRAG
#undef LDB_FRAG
}

// ---------------------------------------------------------------------------
// reduce_psum: rsum[i] = 1 / sum_{j<8} psum[i][j]
// ---------------------------------------------------------------------------
__global__ __launch_bounds__(256) void reduce_psum(const float* __restrict__ p,
                                                   float* __restrict__ r, int n) {
  int i = blockIdx.x * 256 + threadIdx.x;
  if (i < n) {
    const float* q = p + (long)i * 8;
    float s = q[0] + q[1] + q[2] + q[3] + q[4] + q[5] + q[6] + q[7];
    r[i] = 1.0f / s;
  }
}

__global__ void sentinel_kernel(float* out, float v) { out[0] = v; }

// ---------------------------------------------------------------------------
extern "C" void kernel_launch(void* const* d_in, const int* in_sizes, int n_in,
                              void* d_out, int out_size, void* d_ws, size_t ws_size,
                              hipStream_t stream) {
  const float* x  = (const float*)d_in[0];
  const float* Wq = (const float*)d_in[1];
  const float* bq = (const float*)d_in[2];
  const float* Wk = (const float*)d_in[3];
  const float* bk = (const float*)d_in[4];
  const float* Wv = (const float*)d_in[5];
  const float* bv = (const float*)d_in[6];
  float* out = (float*)d_out;

  (void)hipFuncSetAttribute((const void*)gemm256<0>,
      hipFuncAttributeMaxDynamicSharedMemorySize, 135168);
  (void)hipFuncSetAttribute((const void*)gemm256<3>,
      hipFuncAttributeMaxDynamicSharedMemorySize, 135168);
  (void)hipFuncSetAttribute((const void*)gemm256<4>,
      hipFuncAttributeMaxDynamicSharedMemorySize, 135168);

  // Tiers (chosen by ws_size -> constant across calls):
  //  BIG2 (>=208207872): single-shot z=8.
  //    qkv[0,96M): Q[0,32M) K[32,64) VT[64,96)  (VT = V^T per batch [1024][2048])
  //    xb[96,128M) wb[128,134.2M)   (both dead after QKV gemm)
  //    wt[134.2M, 198.2M)  psum[198.2M,+512K)  rsum[+64K)
  //  SMALL2 (>=140509184): 4 passes x z=2; wt(16M)+psum+rsum inside dead xb.
  const size_t NEED_BIG2 = 208207872;
  const size_t NEED_SM2  = 140509184;
  if (ws_size < NEED_SM2) {
    sentinel_kernel<<<1, 1, 0, stream>>>(out, (float)ws_size);
    return;
  }
  const bool big = (ws_size >= NEED_BIG2);
  char* ws = (char*)d_ws;
  unsigned short* qkv = (unsigned short*)(ws);
  unsigned short* xb  = (unsigned short*)(ws + 100663296);
  unsigned short* wb  = (unsigned short*)(ws + 134217728);
  unsigned short* wt  = big ? (unsigned short*)(ws + 140509184)
                            : (unsigned short*)(ws + 100663296);
  float* psum = big ? (float*)(ws + 207618048) : (float*)(ws + 117440512);
  float* rsum = big ? (float*)(ws + 208142336) : (float*)(ws + 117571584);

  const float scale = 0.03125f;  // 1/sqrt(1024)

  pack_bf16<<<dim3(4096), dim3(256), 0, stream>>>(x, xb, 16777216L);
  pack_bf16<<<dim3(1024), dim3(256), 0, stream>>>(Wq, wb, 1048576L);
  pack_bf16<<<dim3(1024), dim3(256), 0, stream>>>(Wk, wb + 1048576, 1048576L);
  pack_bf16<<<dim3(1024), dim3(256), 0, stream>>>(Wv, wb + 2097152, 1048576L);

  // QKV projection: [16384,1024] x [3072,1024]^T -> Q,K row-major + V^T
  gemm256<0><<<dim3(64, 12, 1), dim3(512), 135168, stream>>>(
      xb, 0L, wb, 0L, 1024, 1024, 16,
      nullptr, 0L, 0, 1.0f, qkv, 0L, 1024, bq, bk, bv, nullptr, nullptr);

  const int bpp = big ? 8 : 2;
  const int npasses = 8 / bpp;
  for (int p = 0; p < npasses; ++p) {
    long b0 = (long)p * bpp;
    long boff = b0 * 2048 * 1024;
    // scores: exp(QK^T * scale) -> bf16 weights wt + psum partials
    gemm256<3><<<dim3(8, 8, bpp), dim3(512), 135168, stream>>>(
        qkv + boff, 2048L * 1024, qkv + 16777216 + boff, 2048L * 1024,
        1024, 1024, 16,
        nullptr, 0L, 0, scale, wt, 2048L * 2048, 2048,
        nullptr, nullptr, nullptr, psum, nullptr);

    // row-sum reciprocals
    reduce_psum<<<dim3(8 * bpp), dim3(256), 0, stream>>>(psum, rsum, 2048 * bpp);

    // out = (wt @ V^T-rows) * rsum : fp32
    gemm256<4><<<dim3(8, 4, bpp), dim3(512), 135168, stream>>>(
        wt, 2048L * 2048, qkv + 2L * 16777216 + b0 * 2097152, 2097152L,
        2048, 2048, 32,
        out + boff, 2048L * 1024, 1024, 1.0f, nullptr, 0L, 0,
        nullptr, nullptr, nullptr, nullptr, rsum);
  }
}

// Round 8
// 268.964 us; speedup vs baseline: 1.7661x; 1.0726x over previous
//
#include <hip/hip_runtime.h>

typedef __bf16 bf16x8 __attribute__((ext_vector_type(8)));
typedef float f32x4 __attribute__((ext_vector_type(4)));

__device__ __forceinline__ unsigned short f2bf(float f) {
  unsigned int u = __builtin_bit_cast(unsigned int, f);
  u += 0x7fffu + ((u >> 16) & 1u);
  return (unsigned short)(u >> 16);
}

__device__ __forceinline__ void async16(const void* g, void* l) {
  __builtin_amdgcn_global_load_lds(
      (const __attribute__((address_space(1))) unsigned int*)g,
      (__attribute__((address_space(3))) unsigned int*)l, 16, 0, 0);
}

#define MFMA(a, b, c) __builtin_amdgcn_mfma_f32_16x16x32_bf16((a), (b), (c), 0, 0, 0)

// ---------------------------------------------------------------------------
// pack: fp32 -> bf16 (RNE), vectorized
// ---------------------------------------------------------------------------
__global__ __launch_bounds__(256) void pack_bf16(const float* __restrict__ src,
                                                 unsigned short* __restrict__ dst,
                                                 long n) {
  long i = ((long)blockIdx.x * blockDim.x + threadIdx.x) * 4;
  long stride = (long)gridDim.x * blockDim.x * 4;
  for (; i < n; i += stride) {
    float4 v = *(const float4*)(src + i);
    ushort4 o;
    o.x = f2bf(v.x); o.y = f2bf(v.y); o.z = f2bf(v.z); o.w = f2bf(v.w);
    *(ushort4*)(dst + i) = o;
  }
}

// pack the 3 weight matrices in one launch: grid (1024, 3)
__global__ __launch_bounds__(256) void pack_w3(const float* __restrict__ s0,
                                               const float* __restrict__ s1,
                                               const float* __restrict__ s2,
                                               unsigned short* __restrict__ dst) {
  const float* s = (blockIdx.y == 0) ? s0 : (blockIdx.y == 1) ? s1 : s2;
  long i = ((long)blockIdx.x * 256 + threadIdx.x) * 4;  // covers 1048576 exactly
  float4 v = *(const float4*)(s + i);
  ushort4 o;
  o.x = f2bf(v.x); o.y = f2bf(v.y); o.z = f2bf(v.z); o.w = f2bf(v.w);
  *(ushort4*)(dst + (long)blockIdx.y * 1048576 + i) = o;
}

// ---------------------------------------------------------------------------
// gemm256: C[M,N] = A[M,K] * B[N,K]^T  (row-major bf16, K contiguous)
// 256x256 tile, BK=64, 8 waves (2Mx4N). Round-8 schedule: software-pipelined
// fragment reads (phase p's ds_reads issued during phase p-1; MFMA overlaps
// LDS completion via compiler's counted lgkmcnt), TWO barriers per K-tile:
//   - mid-tile (end of phase 1): orders phase-0 B-register consumption
//     before phases 2/3 restage the B slots of the current buffer.
//   - tile boundary: vmcnt(4) guarantees A(t+1) landed; barrier makes it
//     block-wide; next tile's phase-0 A fragments prefetched right after.
// Staging identical to r6/7 (8 async16/tile, running pointers, clamped tail).
//  EPI 0: QKV: bf16+bias; Q/K row-major; V written TRANSPOSED (V^T[b][d][s]).
//  EPI 3: scores: bf16 exp(s*scale) weights + per-(row,bn) partial sums.
//  EPI 4: PV: fp32 out / rowsum (psum summed inline).
// ---------------------------------------------------------------------------
template <int EPI>
__global__ __launch_bounds__(512, 1) void gemm256(
    const unsigned short* __restrict__ A, long sAz,
    const unsigned short* __restrict__ B, long sBz,
    int lda, int ldb, int nt,
    float* __restrict__ Cf, long sCz, int ldc, float scale,
    unsigned short* __restrict__ Cq, long sQz, int ldq,
    const float* __restrict__ bq, const float* __restrict__ bk,
    const float* __restrict__ bv, float* __restrict__ psum) {
  extern __shared__ __align__(16) char smem[];
  const int tid = threadIdx.x;
  const int l = tid & 63;
  const int w = tid >> 6;
  const int wm = w >> 2, wn = w & 3;
  int bm = blockIdx.x;
  if ((gridDim.x & 7) == 0) {  // XCD-aware swizzle (bijective: gx % 8 == 0)
    int cpx = gridDim.x >> 3;
    bm = (bm & 7) * cpx + (bm >> 3);
  }
  const int bn = blockIdx.y, bz = blockIdx.z;
  const unsigned short* Ab = A + (long)bz * sAz + (long)bm * 256 * lda;
  const unsigned short* Bb = B + (long)bz * sBz + (long)bn * 256 * ldb;

  const int r0 = tid >> 3;                 // staging row 0..63
  const int sch = (tid & 7) ^ (r0 & 7);    // inverse-swizzled source chunk
  const int l15 = l & 15;
  const int kof = (l >> 4) << 3;           // 0,8,16,24

  const int aslot = wm * 16384;
  const int bslot = 32768 + (wn >> 1) * 16384;
  const int brow0 = (wn & 1) * 64;

  // XOR-folded fragment offset cores: aof[fr][ks] = acore[ks] + fr*2048,
  // bof[fc][ks] = bcore[ks] + fc*2048 (mask bits 4-6 never collide with +2048k)
  const int amask = (l15 & 7) << 4;
  const int acore0 = (aslot + l15 * 128 + kof * 2) ^ amask;
  const int acore1 = (aslot + l15 * 128 + 64 + kof * 2) ^ amask;
  const int bcore0 = (bslot + (brow0 + l15) * 128 + kof * 2) ^ amask;
  const int bcore1 = (bslot + (brow0 + l15) * 128 + 64 + kof * 2) ^ amask;

  // running staging pointers (one per 64-row group), +64 elems per tile
  const unsigned short* pa0 = Ab + (long)r0 * lda + sch * 8;
  const unsigned short* pa1 = pa0 + (long)64 * lda;
  const unsigned short* pa2 = pa0 + (long)128 * lda;
  const unsigned short* pa3 = pa0 + (long)192 * lda;
  const unsigned short* pb0 = Bb + (long)r0 * ldb + sch * 8;
  const unsigned short* pb1 = pb0 + (long)64 * ldb;
  const unsigned short* pb2 = pb0 + (long)128 * ldb;
  const unsigned short* pb3 = pb0 + (long)192 * ldb;

  char* sdst = smem + (tid << 4);  // LDS staging dest base (lane-linear)

  f32x4 acc[8][4] = {};
  bf16x8 bfr[4][2];
  bf16x8 c00, c01, c10, c11;  // current-phase A fragments
  bf16x8 n00, n01, n10, n11;  // next-phase A fragments

#define LDA_F(dst, bb, fr, ks) \
  dst = *(const bf16x8*)(smem + (((ks) ? acore1 : acore0) + (fr)*2048 + (bb)));
#define LDB_F(dst, bb, fc, ks) \
  dst = *(const bf16x8*)(smem + (((ks) ? bcore1 : bcore0) + (fc)*2048 + (bb)));

  // prologue staging: B(0), A(0), B(1)  [12 async16]
  async16(pb0, sdst + 32768);         async16(pb1, sdst + 40960);
  async16(pb2, sdst + 49152);         async16(pb3, sdst + 57344);
  async16(pa0, sdst + 0);             async16(pa1, sdst + 8192);
  async16(pa2, sdst + 16384);         async16(pa3, sdst + 24576);
  async16(pb0 + 64, sdst + 98304);    async16(pb1 + 64, sdst + 106496);
  async16(pb2 + 64, sdst + 114688);   async16(pb3 + 64, sdst + 122880);
  asm volatile("s_waitcnt vmcnt(4)" ::: "memory");
  __builtin_amdgcn_s_barrier();
  pa0 += 64; pa1 += 64; pa2 += 64; pa3 += 64;
  pb0 += 128; pb1 += 128; pb2 += 128; pb3 += 128;

  // initial phase-0 A fragments for tile 0 (buf = 0)
  LDA_F(c00, 0, 0, 0); LDA_F(c01, 0, 0, 1);
  LDA_F(c10, 0, 1, 0); LDA_F(c11, 0, 1, 1);

  for (int t = 0; t < nt; ++t) {
    const int buf = (t & 1) << 16;
    const int nbuf = buf ^ 65536;

    // ---- phase 0: read all B + aN(fr2,3); stage A h0(t+1); MFMA aC(fr0,1)
#pragma unroll
    for (int fc = 0; fc < 4; ++fc) {
      LDB_F(bfr[fc][0], buf, fc, 0);
      LDB_F(bfr[fc][1], buf, fc, 1);
    }
    LDA_F(n00, buf, 2, 0); LDA_F(n01, buf, 2, 1);
    LDA_F(n10, buf, 3, 0); LDA_F(n11, buf, 3, 1);
    async16(pa0, sdst + nbuf);
    async16(pa1, sdst + nbuf + 8192);
    __builtin_amdgcn_s_setprio(1);
#pragma unroll
    for (int fc = 0; fc < 4; ++fc) {
      acc[0][fc] = MFMA(c00, bfr[fc][0], acc[0][fc]);
      acc[0][fc] = MFMA(c01, bfr[fc][1], acc[0][fc]);
      acc[1][fc] = MFMA(c10, bfr[fc][0], acc[1][fc]);
      acc[1][fc] = MFMA(c11, bfr[fc][1], acc[1][fc]);
    }
    __builtin_amdgcn_s_setprio(0);

    // ---- phase 1: read aC(fr4,5); stage A h1(t+1); MFMA aN(fr2,3); mid-bar
    LDA_F(c00, buf, 4, 0); LDA_F(c01, buf, 4, 1);
    LDA_F(c10, buf, 5, 0); LDA_F(c11, buf, 5, 1);
    async16(pa2, sdst + nbuf + 16384);
    async16(pa3, sdst + nbuf + 24576);
    __builtin_amdgcn_s_setprio(1);
#pragma unroll
    for (int fc = 0; fc < 4; ++fc) {
      acc[2][fc] = MFMA(n00, bfr[fc][0], acc[2][fc]);
      acc[2][fc] = MFMA(n01, bfr[fc][1], acc[2][fc]);
      acc[3][fc] = MFMA(n10, bfr[fc][0], acc[3][fc]);
      acc[3][fc] = MFMA(n11, bfr[fc][1], acc[3][fc]);
    }
    __builtin_amdgcn_s_setprio(0);
    __builtin_amdgcn_s_barrier();

    // ---- phase 2: read aN(fr6,7); stage B h0(t+2); MFMA aC(fr4,5)
    LDA_F(n00, buf, 6, 0); LDA_F(n01, buf, 6, 1);
    LDA_F(n10, buf, 7, 0); LDA_F(n11, buf, 7, 1);
    async16(pb0, sdst + buf + 32768);
    async16(pb1, sdst + buf + 40960);
    __builtin_amdgcn_s_setprio(1);
#pragma unroll
    for (int fc = 0; fc < 4; ++fc) {
      acc[4][fc] = MFMA(c00, bfr[fc][0], acc[4][fc]);
      acc[4][fc] = MFMA(c01, bfr[fc][1], acc[4][fc]);
      acc[5][fc] = MFMA(c10, bfr[fc][0], acc[5][fc]);
      acc[5][fc] = MFMA(c11, bfr[fc][1], acc[5][fc]);
    }
    __builtin_amdgcn_s_setprio(0);

    // ---- phase 3: stage B h1(t+2); MFMA aN(fr6,7); vmcnt(4)+barrier
    async16(pb2, sdst + buf + 49152);
    async16(pb3, sdst + buf + 57344);
    __builtin_amdgcn_s_setprio(1);
#pragma unroll
    for (int fc = 0; fc < 4; ++fc) {
      acc[6][fc] = MFMA(n00, bfr[fc][0], acc[6][fc]);
      acc[6][fc] = MFMA(n01, bfr[fc][1], acc[6][fc]);
      acc[7][fc] = MFMA(n10, bfr[fc][0], acc[7][fc]);
      acc[7][fc] = MFMA(n11, bfr[fc][1], acc[7][fc]);
    }
    __builtin_amdgcn_s_setprio(0);
    asm volatile("s_waitcnt vmcnt(4)" ::: "memory");
    __builtin_amdgcn_s_barrier();

    // prefetch next tile's phase-0 A fragments from nbuf (A(t+1) landed)
    LDA_F(c00, nbuf, 0, 0); LDA_F(c01, nbuf, 0, 1);
    LDA_F(c10, nbuf, 1, 0); LDA_F(c11, nbuf, 1, 1);

    // pointer advance with clamp (min(t+1,nt-1)/min(t+2,nt-1) semantics)
    if (t < nt - 2) { pa0 += 64; pa1 += 64; pa2 += 64; pa3 += 64; }
    if (t < nt - 3) { pb0 += 64; pb1 += 64; pb2 += 64; pb3 += 64; }
  }

  asm volatile("s_waitcnt vmcnt(0)" ::: "memory");
  __builtin_amdgcn_s_barrier();

  const int rl = (l >> 4) * 4;  // C/D layout: col=lane&15, row=(lane>>4)*4+reg

  if constexpr (EPI == 0) {
    const int which = (bn * 256) >> 10;      // 0=Q 1=K 2=V
    const int colbase = bn * 256 + wn * 64;
    const float* bias = (which == 0) ? bq : (which == 1) ? bk : bv;
    if (which < 2) {
#pragma unroll
      for (int fr = 0; fr < 8; ++fr)
#pragma unroll
        for (int fc = 0; fc < 4; ++fc) {
          int lc = fc * 16 + l15;
          float bv_ = bias[(colbase + lc) & 1023];
#pragma unroll
          for (int rr = 0; rr < 4; ++rr) {
            int lr = fr * 16 + rl + rr;
            int byte = w * 16384 + lr * 128 + lc * 2;
            byte ^= (lr & 7) << 4;
            *(unsigned short*)(smem + byte) = f2bf(acc[fr][fc][rr] + bv_);
          }
        }
      __syncthreads();
      const long brow = (long)bm * 256;
      const int cw0 = (bn * 256) & 1023;
#pragma unroll
      for (int it = 0; it < 16; ++it) {
        int f = it * 512 + tid;
        int r = f >> 5, ch = f & 31;
        int wv = (r >> 7) * 4 + (ch >> 3);
        int byte = wv * 16384 + (r & 127) * 128 + (ch & 7) * 16;
        byte ^= (r & 7) << 4;
        uint4 val = *(const uint4*)(smem + byte);
        unsigned short* d = Cq + (long)which * 16777216L +
                            (brow + r) * 1024 + cw0 + ch * 8;
        *(uint4*)d = val;
      }
    } else {
      // V: transposed staging [c][r] -> write V^T[b][d][s] coalesced
#pragma unroll
      for (int fr = 0; fr < 8; ++fr)
#pragma unroll
        for (int fc = 0; fc < 4; ++fc) {
          int lc = wn * 64 + fc * 16 + l15;
          float bv_ = bias[(colbase + fc * 16 + l15) & 1023];
#pragma unroll
          for (int rr = 0; rr < 4; ++rr) {
            int r = wm * 128 + fr * 16 + rl + rr;
            int byte = lc * 512 + r * 2;
            byte ^= (lc & 7) << 4;
            *(unsigned short*)(smem + byte) = f2bf(acc[fr][fc][rr] + bv_);
          }
        }
      __syncthreads();
      const long brow = (long)bm * 256;
      const long b = brow >> 11;
      const long s0 = brow & 2047;
      unsigned short* VT = Cq + 2L * 16777216;
#pragma unroll
      for (int it = 0; it < 16; ++it) {
        int f = it * 512 + tid;
        int c = f >> 5, ch = f & 31;
        int byte = (c * 512 + ch * 16) ^ ((c & 7) << 4);
        uint4 val = *(const uint4*)(smem + byte);
        int d = (bn * 256 - 2048) + c;
        unsigned short* dst = VT + b * 2097152 + (long)d * 2048 + s0 + ch * 8;
        *(uint4*)dst = val;
      }
    }
  } else if constexpr (EPI == 3) {
    // scores: w = exp(s*scale) -> bf16 staged; per-row partial sums
    float rs[4];
#pragma unroll
    for (int fr = 0; fr < 8; ++fr) {
      rs[0] = rs[1] = rs[2] = rs[3] = 0.0f;
#pragma unroll
      for (int fc = 0; fc < 4; ++fc) {
        int lc = fc * 16 + l15;
#pragma unroll
        for (int rr = 0; rr < 4; ++rr) {
          float e = __expf(acc[fr][fc][rr] * scale);
          rs[rr] += e;
          int lr = fr * 16 + rl + rr;
          int byte = w * 16384 + lr * 128 + lc * 2;
          byte ^= (lr & 7) << 4;
          *(unsigned short*)(smem + byte) = f2bf(e);
        }
      }
#pragma unroll
      for (int rr = 0; rr < 4; ++rr) {
        float v = rs[rr];
#pragma unroll
        for (int o = 1; o < 16; o <<= 1) v += __shfl_xor(v, o);
        if (l15 == 0) {
          int row = wm * 128 + fr * 16 + rl + rr;
          *(float*)(smem + 131072 + (wn * 256 + row) * 4) = v;
        }
      }
    }
    __syncthreads();
    const long brow = (long)bm * 256;
#pragma unroll
    for (int it = 0; it < 16; ++it) {
      int f = it * 512 + tid;
      int r = f >> 5, ch = f & 31;
      int wv = (r >> 7) * 4 + (ch >> 3);
      int byte = wv * 16384 + (r & 127) * 128 + (ch & 7) * 16;
      byte ^= (r & 7) << 4;
      uint4 val = *(const uint4*)(smem + byte);
      unsigned short* d = Cq + (long)bz * sQz + (brow + r) * ldq + bn * 256 + ch * 8;
      *(uint4*)d = val;
    }
    if (tid < 256) {
      float s4 = *(const float*)(smem + 131072 + tid * 4) +
                 *(const float*)(smem + 131072 + 1024 + tid * 4) +
                 *(const float*)(smem + 131072 + 2048 + tid * 4) +
                 *(const float*)(smem + 131072 + 3072 + tid * 4);
      psum[(((long)bz * 2048) + brow + tid) * 8 + bn] = s4;
    }
  } else {  // EPI == 4: PV, normalize by inline psum row-sum
    float* C = Cf + (long)bz * sCz;
    const long grbase = (long)bm * 256 + wm * 128;
    const int gcbase = bn * 256 + wn * 64;
#pragma unroll
    for (int fr = 0; fr < 8; ++fr)
#pragma unroll
      for (int rr = 0; rr < 4; ++rr) {
        long gr = grbase + fr * 16 + rl + rr;
        const float* pp = psum + (((long)bz * 2048) + gr) * 8;
        float4 s0 = *(const float4*)pp;
        float4 s1 = *(const float4*)(pp + 4);
        float inv = 1.0f / (s0.x + s0.y + s0.z + s0.w +
                            s1.x + s1.y + s1.z + s1.w);
#pragma unroll
        for (int fc = 0; fc < 4; ++fc)
          C[gr * ldc + gcbase + fc * 16 + l15] = acc[fr][fc][rr] * inv;
      }
  }
#undef LDA_F
#undef LDB_F
}

__global__ void sentinel_kernel(float* out, float v) { out[0] = v; }

// ---------------------------------------------------------------------------
extern "C" void kernel_launch(void* const* d_in, const int* in_sizes, int n_in,
                              void* d_out, int out_size, void* d_ws, size_t ws_size,
                              hipStream_t stream) {
  const float* x  = (const float*)d_in[0];
  const float* Wq = (const float*)d_in[1];
  const float* bq = (const float*)d_in[2];
  const float* Wk = (const float*)d_in[3];
  const float* bk = (const float*)d_in[4];
  const float* Wv = (const float*)d_in[5];
  const float* bv = (const float*)d_in[6];
  float* out = (float*)d_out;

  (void)hipFuncSetAttribute((const void*)gemm256<0>,
      hipFuncAttributeMaxDynamicSharedMemorySize, 135168);
  (void)hipFuncSetAttribute((const void*)gemm256<3>,
      hipFuncAttributeMaxDynamicSharedMemorySize, 135168);
  (void)hipFuncSetAttribute((const void*)gemm256<4>,
      hipFuncAttributeMaxDynamicSharedMemorySize, 135168);

  // Tiers (chosen by ws_size -> constant across calls):
  //  BIG2 (>=208207872): single-shot z=8.
  //    qkv[0,96M): Q[0,32M) K[32,64) VT[64,96)
  //    xb[96,128M) wb[128,134.2M) (dead after QKV)  wt[134.2M,198.2M)
  //    psum[198.2M,+512K)
  //  SMALL2 (>=140509184): 4 passes x z=2; wt(16M)+psum inside dead xb.
  const size_t NEED_BIG2 = 208207872;
  const size_t NEED_SM2  = 140509184;
  if (ws_size < NEED_SM2) {
    sentinel_kernel<<<1, 1, 0, stream>>>(out, (float)ws_size);
    return;
  }
  const bool big = (ws_size >= NEED_BIG2);
  char* ws = (char*)d_ws;
  unsigned short* qkv = (unsigned short*)(ws);
  unsigned short* xb  = (unsigned short*)(ws + 100663296);
  unsigned short* wb  = (unsigned short*)(ws + 134217728);
  unsigned short* wt  = big ? (unsigned short*)(ws + 140509184)
                            : (unsigned short*)(ws + 100663296);
  float* psum = big ? (float*)(ws + 207618048) : (float*)(ws + 117440512);

  const float scale = 0.03125f;  // 1/sqrt(1024)

  pack_bf16<<<dim3(4096), dim3(256), 0, stream>>>(x, xb, 16777216L);
  pack_w3<<<dim3(1024, 3), dim3(256), 0, stream>>>(Wq, Wk, Wv, wb);

  // QKV projection: [16384,1024] x [3072,1024]^T -> Q,K row-major + V^T
  gemm256<0><<<dim3(64, 12, 1), dim3(512), 135168, stream>>>(
      xb, 0L, wb, 0L, 1024, 1024, 16,
      nullptr, 0L, 0, 1.0f, qkv, 0L, 1024, bq, bk, bv, nullptr);

  const int bpp = big ? 8 : 2;
  const int npasses = 8 / bpp;
  for (int p = 0; p < npasses; ++p) {
    long b0 = (long)p * bpp;
    long boff = b0 * 2048 * 1024;
    // scores: exp(QK^T * scale) -> bf16 weights wt + psum partials
    gemm256<3><<<dim3(8, 8, bpp), dim3(512), 135168, stream>>>(
        qkv + boff, 2048L * 1024, qkv + 16777216 + boff, 2048L * 1024,
        1024, 1024, 16,
        nullptr, 0L, 0, scale, wt, 2048L * 2048, 2048,
        nullptr, nullptr, nullptr, psum);

    // out = (wt @ V^T-rows) / rowsum : fp32
    gemm256<4><<<dim3(8, 4, bpp), dim3(512), 135168, stream>>>(
        wt, 2048L * 2048, qkv + 2L * 16777216 + b0 * 2097152, 2097152L,
        2048, 2048, 32,
        out + boff, 2048L * 1024, 1024, 1.0f, nullptr, 0L, 0,
        nullptr, nullptr, nullptr, psum);
  }
}